// Round 5
// baseline (1578.439 us; speedup 1.0000x reference)
//
#include <hip/hip_runtime.h>
#include <stdint.h>
#include <stddef.h>

// ---------------------------------------------------------------------------
// TextRNN: embed -> BiLSTM(512 steps) -> linear -> softmax   (MI355X gfx950)
//
// R8 structure (delta vs R7):
// * DEFERRED mirror publish: epilogue issues only 4 sc0 primary stores.
//   The sc1 mirror words (tag t, kept in regs) are issued inside step t's
//   poll asm AFTER the poll loads -> first-round wait is vmcnt(4)
//   (mirrors are the 4 newest ops, excluded from the wait). Mirror is
//   still published unconditionally BEFORE any spin -> guaranteed
//   progress under any placement (hang-proof), but its MALL ack is now
//   OFF the critical path (drained a full step later).
// * Zero compiler VMEM in the hot loop: tokens preloaded to LDS, emb
//   prefetch folded into the poll asm, Wx fragments in registers (like
//   Wh). Raw s_barrier + manual lgkmcnt(0) instead of __syncthreads()
//   (avoids the compiler's vmcnt(0)-before-barrier drain).
// * K3 reads the PRIMARY buffer (dispatch-boundary cache flush makes
//   prior-kernel stores visible, as for any normal store).
// K0 : transpose/cast Wx,Wh (f32 [256][1024]) -> bf16 [1024][256]
// K0b: cast emb table f32 -> bf16
// K2 : fused zx + recurrence (32 blocks = 8 groups x 4 cg, 256 thr)
// K3 : logits + softmax
// ---------------------------------------------------------------------------

typedef __attribute__((ext_vector_type(8))) short   short8;
typedef __attribute__((ext_vector_type(4))) float   f32x4;
typedef __attribute__((ext_vector_type(4))) unsigned short ushort4v;
typedef __attribute__((ext_vector_type(4))) unsigned int   uint4v;
typedef __attribute__((ext_vector_type(2))) unsigned int   uint2v;

// ws byte offsets
#define EMB16_OFF ((size_t)0)            // 50000*256 bf16 = 25,600,000 B
#define WXT_OFF   ((size_t)25600000)     // 2*1024*256 bf16 = 1,048,576 B
#define WHT_OFF   ((size_t)26648576)     // 2*1024*256 bf16 = 1,048,576 B
#define HBUF_OFF  ((size_t)27697152)     // primary 262,144 B + mirror 262,144 B
#define WS_NEED   ((size_t)28221440)

__device__ __forceinline__ unsigned short f2bf(float f) {
  unsigned int u = __builtin_bit_cast(unsigned int, f);
  u += 0x7fffu + ((u >> 16) & 1u);            // RNE
  return (unsigned short)(u >> 16);
}
__device__ __forceinline__ float bf2f(unsigned short b) {
  unsigned int u = ((unsigned int)b) << 16;
  return __builtin_bit_cast(float, u);
}
__device__ __forceinline__ float sigf(float x) { return 1.0f / (1.0f + __expf(-x)); }
__device__ __forceinline__ float tanhf_(float x) {
  float t = __expf(-2.0f * fabsf(x));
  float r = (1.0f - t) / (1.0f + t);          // no inf/NaN for any x
  return copysignf(r, x);
}

// ---------------------------------------------------------------------------
// K0: W (f32 [256][1024]) -> Wt (bf16 [1024][256]).  z selects matrix.
__global__ __launch_bounds__(256) void k0_transpose(
    const float* __restrict__ wxf, const float* __restrict__ wxb,
    const float* __restrict__ whf, const float* __restrict__ whb,
    unsigned short* __restrict__ wxt, unsigned short* __restrict__ wht) {
  __shared__ float lds[32][33];
  int mat = blockIdx.z;
  const float* src = (mat == 0) ? wxf : (mat == 1) ? wxb : (mat == 2) ? whf : whb;
  unsigned short* dst = (mat == 0) ? wxt : (mat == 1) ? (wxt + 262144)
                      : (mat == 2) ? wht : (wht + 262144);
  int k0 = blockIdx.x * 32;
  int n0 = blockIdx.y * 32;
  int tx = threadIdx.x & 31, ty = threadIdx.x >> 5;   // ty 0..7
#pragma unroll
  for (int r = 0; r < 4; r++) {
    int k = ty + r * 8;
    lds[k][tx] = src[(size_t)(k0 + k) * 1024 + n0 + tx];
  }
  __syncthreads();
#pragma unroll
  for (int r = 0; r < 4; r++) {
    int n = ty + r * 8;
    dst[(size_t)(n0 + n) * 256 + k0 + tx] = f2bf(lds[tx][n]);
  }
}

// ---------------------------------------------------------------------------
// K0b: emb table f32 -> bf16.  50000*256 = 12.8M elems, 8/thread, 6250 blocks.
__global__ __launch_bounds__(256) void k0b_embcast(
    const float* __restrict__ emb, unsigned short* __restrict__ embbf) {
  size_t i = ((size_t)blockIdx.x * 256 + threadIdx.x) * 8;
  f32x4 v0 = *(const f32x4*)(emb + i);
  f32x4 v1 = *(const f32x4*)(emb + i + 4);
  short8 st;
#pragma unroll
  for (int j = 0; j < 4; j++) {
    st[j]     = (short)f2bf(v0[j]);
    st[4 + j] = (short)f2bf(v1[j]);
  }
  *(short8*)(embbf + i) = st;
}

// ---------------------------------------------------------------------------
// K2: fused zx + recurrence. 32 blocks, 256 thr (4 waves).
// Group gid = bid&7 -> (d = gid>>2, rg = gid&3); member cg = bid>>3.
// (Round-robin dispatch puts a group's 4 members on one XCD; SPEED
//  heuristic only — correctness never depends on placement.)
// Block (d,rg,cg): batch rows rg*16..+16, h-dims cg*64..+64 (all 4 gates).
// Wave w: dims w*16..+16; lane (q,l16): rows q*4..+4, dim w*16+l16;
// gate-major accumulators (cs = gate) -> c-state in registers.
// hbuf primary: [gid][buf][row 16][dim 256] tagged u32 ((t<<16)|bf16), sc0.
// hbuf mirror : same layout at +65536 words, sc1 (deferred publish).
__global__ __launch_bounds__(256, 1) void k2_rnn(
    const int* __restrict__ tokens, const unsigned short* __restrict__ embbf,
    const unsigned short* __restrict__ wxt,   // [2][1024][256] bf16
    const unsigned short* __restrict__ wht,   // [2][1024][256] bf16
    const float* __restrict__ bf_, const float* __restrict__ bb_,
    unsigned int* __restrict__ hbufw) {
  int bx = blockIdx.x;
  int gid = bx & 7;
  int cg  = bx >> 3;
  int d   = gid >> 2;
  int rg  = gid & 3;
  int tid = threadIdx.x;
  int w = tid >> 6, lane = tid & 63, q = lane >> 4, l16 = lane & 15;

  __shared__ unsigned int   tl[16][520];        // tokens, padded rows: 33 KB
  __shared__ unsigned short hl[2][32][16][8];   // h tiles, interleaved: 16 KB

  // ---- token preload (this block's 16 batch rows) ----
  for (int i = tid; i < 8192; i += 256) {
    int row = i >> 9, col = i & 511;
    tl[row][col] = (unsigned int)tokens[(rg * 16 + row) * 512 + col];
  }

  // ---- Wx and Wh B-fragments resident in registers (128+128 regs/lane) ----
  const unsigned short* wxd = wxt + (size_t)d * 262144;
  const unsigned short* whd = wht + (size_t)d * 262144;
  short8 xfr[4][8], bfr[4][8];
#pragma unroll
  for (int cs = 0; cs < 4; cs++) {
    const unsigned short* xp = wxd + (size_t)(cs * 256 + cg * 64 + w * 16 + l16) * 256;
    const unsigned short* wp = whd + (size_t)(cs * 256 + cg * 64 + w * 16 + l16) * 256;
#pragma unroll
    for (int kt = 0; kt < 8; kt++) {
      xfr[cs][kt] = *(const short8*)(xp + kt * 32 + q * 8);
      bfr[cs][kt] = *(const short8*)(wp + kt * 32 + q * 8);
    }
  }

  // zero h LDS tiles (h0 = 0)
  {
    unsigned int* hlw = (unsigned int*)&hl[0][0][0][0];
    for (int i = tid; i < 4096; i += 256) hlw[i] = 0;
  }
  __syncthreads();    // setup barrier (one-time full drain is fine)

  const float* bias = d ? bb_ : bf_;
  float bv[4];
#pragma unroll
  for (int cs = 0; cs < 4; cs++) bv[cs] = bias[cs * 256 + cg * 64 + w * 16 + l16];

  float cst[4] = {0.f, 0.f, 0.f, 0.f};        // c for (row=q*4+r, dim=w*16+l16)
  unsigned int* hb = hbufw + (size_t)gid * 8192;            // primary
  unsigned int* mb = hb + 65536;                            // mirror
  int prow = w * 4 + q;                        // this wave's poll rows
  int ps   = lane & 15;                        // dim quad within 64
  int rcg0 = (cg + 1) & 3, rcg1 = (cg + 2) & 3, rcg2 = (cg + 3) & 3;
  int pbase = prow * 256 + ps * 4;            // words
  int srow  = (q * 4) * 256 + cg * 64 + w * 16 + l16;       // producer base

  int limit = 16;                              // sc0 retry budget (decays)
  unsigned int swm[4] = {0u, 0u, 0u, 0u};      // deferred mirror words (tag t)

  // prologue: emb row for t=0 (compiler loads; drained before first use)
  short8 eaA[8], eaB[8];
  {
    int ts0 = d ? 511 : 0;
    unsigned int tok0 = tl[l16][ts0];
    const unsigned short* er = embbf + (size_t)tok0 * 256 + q * 8;
#pragma unroll
    for (int kt = 0; kt < 8; ++kt) eaA[kt] = *(const short8*)(er + kt * 32);
  }

  auto step = [&](int t, short8 (&ea)[8], short8 (&en)[8]) {
    int buf = t & 1;
    int tsn = (t < 511) ? (d ? 510 - t : t + 1) : 0;   // next-step token col
    unsigned int tokn = tl[l16][tsn];                  // LDS (lgkm only)
    const unsigned short* ern = embbf + (size_t)tokn * 256 + q * 8;

    // ---- zx tile MFMA from registers (h-independent; overlaps sc0 drain) --
    f32x4 acc[4];
#pragma unroll
    for (int cs = 0; cs < 4; ++cs) acc[cs] = {0.f, 0.f, 0.f, 0.f};
#pragma unroll
    for (int kt = 0; kt < 8; ++kt)
#pragma unroll
      for (int cs = 0; cs < 4; ++cs)
        acc[cs] = __builtin_amdgcn_mfma_f32_16x16x32_bf16(ea[kt], xfr[cs][kt], acc[cs], 0, 0, 0);

    // ---- round 1: poll loads + emb prefetch + DEFERRED mirror publish ----
    // Issue order: 3 sc0 poll loads, 8 emb loads, 4 sc1 mirror stores.
    // vmcnt(4): drains everything except the 4 mirrors (newest) -> poll
    // loads + emb valid; mirror MALL ack drifts to later steps' waits.
    const unsigned int* q0 = hb + buf * 4096 + pbase + rcg0 * 64;
    const unsigned int* q1 = hb + buf * 4096 + pbase + rcg1 * 64;
    const unsigned int* q2 = hb + buf * 4096 + pbase + rcg2 * 64;
    unsigned int* hwm = mb + buf * 4096 + srow;
    unsigned int tg = (unsigned int)t << 16;
    uint4v r0, r1, r2;
    asm volatile(
        "global_load_dwordx4 %[r0], %[p0], off sc0\n\t"
        "global_load_dwordx4 %[r1], %[p1], off sc0\n\t"
        "global_load_dwordx4 %[r2], %[p2], off sc0\n\t"
        "global_load_dwordx4 %[e0], %[pe], off\n\t"
        "global_load_dwordx4 %[e1], %[pe], off offset:64\n\t"
        "global_load_dwordx4 %[e2], %[pe], off offset:128\n\t"
        "global_load_dwordx4 %[e3], %[pe], off offset:192\n\t"
        "global_load_dwordx4 %[e4], %[pe], off offset:256\n\t"
        "global_load_dwordx4 %[e5], %[pe], off offset:320\n\t"
        "global_load_dwordx4 %[e6], %[pe], off offset:384\n\t"
        "global_load_dwordx4 %[e7], %[pe], off offset:448\n\t"
        "global_store_dword %[m], %[s0], off sc1\n\t"
        "global_store_dword %[m], %[s1], off offset:1024 sc1\n\t"
        "global_store_dword %[m], %[s2], off offset:2048 sc1\n\t"
        "global_store_dword %[m], %[s3], off offset:3072 sc1\n\t"
        "s_waitcnt vmcnt(4)"
        : [r0] "=&v"(r0), [r1] "=&v"(r1), [r2] "=&v"(r2),
          [e0] "=&v"(en[0]), [e1] "=&v"(en[1]), [e2] "=&v"(en[2]), [e3] "=&v"(en[3]),
          [e4] "=&v"(en[4]), [e5] "=&v"(en[5]), [e6] "=&v"(en[6]), [e7] "=&v"(en[7])
        : [p0] "v"(q0), [p1] "v"(q1), [p2] "v"(q2), [pe] "v"(ern),
          [m] "v"(hwm), [s0] "v"(swm[0]), [s1] "v"(swm[1]),
          [s2] "v"(swm[2]), [s3] "v"(swm[3])
        : "memory");
    {
      unsigned int bad = (r0[0] ^ tg) | (r0[1] ^ tg) | (r0[2] ^ tg) | (r0[3] ^ tg)
                       | (r1[0] ^ tg) | (r1[1] ^ tg) | (r1[2] ^ tg) | (r1[3] ^ tg)
                       | (r2[0] ^ tg) | (r2[1] ^ tg) | (r2[2] ^ tg) | (r2[3] ^ tg);
      bool ok = __all((bad & 0xffff0000u) == 0);
      // sc0 retries (budgeted)
      int iters = limit;
      while (!ok && iters-- > 0) {
        asm volatile(
            "global_load_dwordx4 %[r0], %[p0], off sc0\n\t"
            "global_load_dwordx4 %[r1], %[p1], off sc0\n\t"
            "global_load_dwordx4 %[r2], %[p2], off sc0\n\t"
            "s_waitcnt vmcnt(0)"
            : [r0] "=&v"(r0), [r1] "=&v"(r1), [r2] "=&v"(r2)
            : [p0] "v"(q0), [p1] "v"(q1), [p2] "v"(q2)
            : "memory");
        bad = (r0[0] ^ tg) | (r0[1] ^ tg) | (r0[2] ^ tg) | (r0[3] ^ tg)
            | (r1[0] ^ tg) | (r1[1] ^ tg) | (r1[2] ^ tg) | (r1[3] ^ tg)
            | (r2[0] ^ tg) | (r2[1] ^ tg) | (r2[2] ^ tg) | (r2[3] ^ tg);
        ok = __all((bad & 0xffff0000u) == 0);
      }
      if (!ok) {
        limit >>= 1;                           // sticky decay toward sc1-only
        const unsigned int* m0 = q0 + 65536;
        const unsigned int* m1 = q1 + 65536;
        const unsigned int* m2 = q2 + 65536;
        do {
          asm volatile(
              "global_load_dwordx4 %[r0], %[p0], off sc1\n\t"
              "global_load_dwordx4 %[r1], %[p1], off sc1\n\t"
              "global_load_dwordx4 %[r2], %[p2], off sc1\n\t"
              "s_waitcnt vmcnt(0)"
              : [r0] "=&v"(r0), [r1] "=&v"(r1), [r2] "=&v"(r2)
              : [p0] "v"(m0), [p1] "v"(m1), [p2] "v"(m2)
              : "memory");
          bad = (r0[0] ^ tg) | (r0[1] ^ tg) | (r0[2] ^ tg) | (r0[3] ^ tg)
              | (r1[0] ^ tg) | (r1[1] ^ tg) | (r1[2] ^ tg) | (r1[3] ^ tg)
              | (r2[0] ^ tg) | (r2[1] ^ tg) | (r2[2] ^ tg) | (r2[3] ^ tg);
          ok = __all((bad & 0xffff0000u) == 0);
        } while (!ok);
      }
    }

    // deposit packed bf16 into hl[buf] (remote dims; own dims already there)
    {
      int e4 = (ps & 1) * 4, ch2 = ps >> 1;
      uint2v w0, w1, w2;
      w0[0] = __builtin_amdgcn_perm(r0[1], r0[0], 0x05040100u);
      w0[1] = __builtin_amdgcn_perm(r0[3], r0[2], 0x05040100u);
      w1[0] = __builtin_amdgcn_perm(r1[1], r1[0], 0x05040100u);
      w1[1] = __builtin_amdgcn_perm(r1[3], r1[2], 0x05040100u);
      w2[0] = __builtin_amdgcn_perm(r2[1], r2[0], 0x05040100u);
      w2[1] = __builtin_amdgcn_perm(r2[3], r2[2], 0x05040100u);
      *(uint2v*)(&hl[buf][rcg0 * 8 + ch2][prow][e4]) = w0;
      *(uint2v*)(&hl[buf][rcg1 * 8 + ch2][prow][e4]) = w1;
      *(uint2v*)(&hl[buf][rcg2 * 8 + ch2][prow][e4]) = w2;
    }
    // raw barrier: LDS-only drain; sc0/sc1 stores stay outstanding.
    asm volatile("s_waitcnt lgkmcnt(0)" ::: "memory");
    __builtin_amdgcn_s_barrier();

    // ---- h GEMM: A from LDS tile (conflict-free b128), B from regs ----
#pragma unroll
    for (int kt = 0; kt < 8; ++kt) {
      short8 ha = *(const short8*)(&hl[buf][kt * 4 + q][l16][0]);
#pragma unroll
      for (int cs = 0; cs < 4; ++cs)
        acc[cs] = __builtin_amdgcn_mfma_f32_16x16x32_bf16(ha, bfr[cs][kt], acc[cs], 0, 0, 0);
    }

    // ---- epilogue: gates, c/h update, LDS own-dims, 4 sc0 stores ----
    unsigned int* hwn = hb + ((buf ^ 1) * 4096) + srow;
    unsigned int wtag = ((unsigned int)(t + 1)) << 16;
    int dim = cg * 64 + w * 16 + l16;
    int chO = dim >> 3, eO = dim & 7;
    unsigned int sw0, sw1, sw2, sw3;
    {
      float iv, fv, gv, ov, hv;
      iv = sigf(acc[0][0] + bv[0]); fv = sigf(acc[1][0] + bv[1]);
      gv = tanhf_(acc[2][0] + bv[2]); ov = sigf(acc[3][0] + bv[3]);
      cst[0] = fv * cst[0] + iv * gv; hv = ov * tanhf_(cst[0]);
      sw0 = wtag | (unsigned int)f2bf(hv); hl[buf ^ 1][chO][q * 4 + 0][eO] = (unsigned short)(sw0 & 0xffffu);
      iv = sigf(acc[0][1] + bv[0]); fv = sigf(acc[1][1] + bv[1]);
      gv = tanhf_(acc[2][1] + bv[2]); ov = sigf(acc[3][1] + bv[3]);
      cst[1] = fv * cst[1] + iv * gv; hv = ov * tanhf_(cst[1]);
      sw1 = wtag | (unsigned int)f2bf(hv); hl[buf ^ 1][chO][q * 4 + 1][eO] = (unsigned short)(sw1 & 0xffffu);
      iv = sigf(acc[0][2] + bv[0]); fv = sigf(acc[1][2] + bv[1]);
      gv = tanhf_(acc[2][2] + bv[2]); ov = sigf(acc[3][2] + bv[3]);
      cst[2] = fv * cst[2] + iv * gv; hv = ov * tanhf_(cst[2]);
      sw2 = wtag | (unsigned int)f2bf(hv); hl[buf ^ 1][chO][q * 4 + 2][eO] = (unsigned short)(sw2 & 0xffffu);
      iv = sigf(acc[0][3] + bv[0]); fv = sigf(acc[1][3] + bv[1]);
      gv = tanhf_(acc[2][3] + bv[2]); ov = sigf(acc[3][3] + bv[3]);
      cst[3] = fv * cst[3] + iv * gv; hv = ov * tanhf_(cst[3]);
      sw3 = wtag | (unsigned int)f2bf(hv); hl[buf ^ 1][chO][q * 4 + 3][eO] = (unsigned short)(sw3 & 0xffffu);
    }
    // 4 sc0 primary stores, un-drained (next round-1 vmcnt(4) drains them,
    // overlapped with zx MFMA). Mirror words deferred to next step's poll.
    asm volatile(
        "global_store_dword %[p], %[v0], off sc0\n\t"
        "global_store_dword %[p], %[v1], off offset:1024 sc0\n\t"
        "global_store_dword %[p], %[v2], off offset:2048 sc0\n\t"
        "global_store_dword %[p], %[v3], off offset:3072 sc0"
        :: [p] "v"(hwn), [v0] "v"(sw0), [v1] "v"(sw1),
           [v2] "v"(sw2), [v3] "v"(sw3)
        : "memory");
    swm[0] = sw0; swm[1] = sw1; swm[2] = sw2; swm[3] = sw3;
  };

  for (int t2 = 0; t2 < 512; t2 += 2) {
    step(t2,     eaA, eaB);
    step(t2 + 1, eaB, eaA);
  }
}

// ---------------------------------------------------------------------------
// K3: logits + softmax. 64 blocks (one per batch) x 64 threads (one wave).
// Final h_512 (tag 512, buf0) read from the PRIMARY buffers; the k2->k3
// dispatch boundary flushes caches (standard cross-kernel visibility).
__global__ __launch_bounds__(64) void k3_out(
    const unsigned int* __restrict__ hbufw,
    const float* __restrict__ wout, const float* __restrict__ bout,
    float* __restrict__ out) {
  int b = blockIdx.x, tid = threadIdx.x;
  int rg = b >> 4, r = b & 15;
  const unsigned int* hf  = hbufw + (size_t)rg * 8192 + r * 256;           // dir0 buf0
  const unsigned int* hbk = hbufw + 32768 + (size_t)rg * 8192 + r * 256;   // dir1 buf0
  float p[10];
#pragma unroll
  for (int l = 0; l < 10; l++) p[l] = 0.f;
  for (int k = tid; k < 512; k += 64) {
    unsigned int wd = (k < 256) ? hf[k] : hbk[k - 256];
    float f = bf2f((unsigned short)(wd & 0xffffu));
    const float* wr = wout + k * 10;
#pragma unroll
    for (int l = 0; l < 10; l++) p[l] += f * wr[l];
  }
#pragma unroll
  for (int off = 32; off; off >>= 1)
#pragma unroll
    for (int l = 0; l < 10; l++) p[l] += __shfl_down(p[l], off);
  if (tid == 0) {
    float lg[10], m = -1e30f;
#pragma unroll
    for (int l = 0; l < 10; l++) { lg[l] = p[l] + bout[l]; m = fmaxf(m, lg[l]); }
    float sum = 0.f;
#pragma unroll
    for (int l = 0; l < 10; l++) { lg[l] = __expf(lg[l] - m); sum += lg[l]; }
    float inv = 1.0f / sum;
#pragma unroll
    for (int l = 0; l < 10; l++) out[b * 10 + l] = lg[l] * inv;
  }
}

// ---------------------------------------------------------------------------
extern "C" void kernel_launch(void* const* d_in, const int* in_sizes, int n_in,
                              void* d_out, int out_size, void* d_ws, size_t ws_size,
                              hipStream_t stream) {
  const int*   tokens = (const int*)d_in[0];
  const float* emb    = (const float*)d_in[1];
  const float* wxf    = (const float*)d_in[2];
  const float* whf    = (const float*)d_in[3];
  const float* bf_    = (const float*)d_in[4];
  const float* wxb    = (const float*)d_in[5];
  const float* whb    = (const float*)d_in[6];
  const float* bb_    = (const float*)d_in[7];
  const float* wout   = (const float*)d_in[8];
  const float* bout   = (const float*)d_in[9];
  float* out = (float*)d_out;

  char* ws = (char*)d_ws;
  unsigned short* embbf = (unsigned short*)(ws + EMB16_OFF);
  unsigned short* wxt   = (unsigned short*)(ws + WXT_OFF);
  unsigned short* wht   = (unsigned short*)(ws + WHT_OFF);
  unsigned int*   hbufw = (unsigned int*)(ws + HBUF_OFF);
  (void)ws_size; (void)in_sizes; (void)n_in; (void)out_size;   // needs WS_NEED bytes

  // zero h0 (tag 0 == step 0) in primary AND mirror buffers
  hipMemsetAsync(ws + HBUF_OFF, 0, 524288, stream);

  k0_transpose<<<dim3(8, 32, 4), 256, 0, stream>>>(wxf, wxb, whf, whb, wxt, wht);
  k0b_embcast<<<6250, 256, 0, stream>>>(emb, embbf);
  k2_rnn<<<32, 256, 0, stream>>>(tokens, embbf, wxt, wht, bf_, bb_, hbufw);
  k3_out<<<64, 64, 0, stream>>>(hbufw, wout, bout, out);
}

// Round 7
// 1533.677 us; speedup vs baseline: 1.0292x; 1.0292x over previous
//
#include <hip/hip_runtime.h>
#include <stdint.h>
#include <stddef.h>

// ---------------------------------------------------------------------------
// TextRNN: embed -> BiLSTM(512 steps) -> linear -> softmax   (MI355X gfx950)
//
// R9 (resubmit; prior round was an infra failure — kernel audited for
// hang modes: vmcnt accounting, deadlock/progress, mirror overwrite —
// all sound):
// * Round-1 asm issue order [3 poll sc0][8 emb][4 mirror sc1], wait
//   vmcnt(12): in-order retirement means ONLY the 3 poll loads are
//   drained before the tag check. R8's order put the 8 emb gathers
//   (L3/HBM latency, 300-900ns) ahead of the wait point -> every step
//   serialized a full emb-gather before the tag check (+154us).
// * End-of-step vmcnt(8) + sched_barrier(0) (rule: hipcc hoists
//   register-only MFMA past inline-asm waitcnt) guarantees emb loads
//   retired before the NEXT step's zx MFMA consumes them; mirror +
//   primary store acks (8 newest) stay outstanding across steps.
// * Epilogue sc0 stores issued per-row right after each sw[r] is
//   computed -> partners observe tags ~0.1us earlier (less skew).
// * Unchanged from R8: dual-publish sc0-primary/sc1-mirror (hang-proof
//   under any placement), zero compiler VMEM in the loop, tokens in
//   LDS, Wx+Wh fragments in registers, raw s_barrier (LDS-only drain).
// K0 : transpose/cast Wx,Wh (f32 [256][1024]) -> bf16 [1024][256]
// K0b: cast emb table f32 -> bf16
// K2 : fused zx + recurrence (32 blocks = 8 groups x 4 cg, 256 thr)
// K3 : logits + softmax (reads primary; dispatch boundary flushes)
// ---------------------------------------------------------------------------

typedef __attribute__((ext_vector_type(8))) short   short8;
typedef __attribute__((ext_vector_type(4))) float   f32x4;
typedef __attribute__((ext_vector_type(4))) unsigned short ushort4v;
typedef __attribute__((ext_vector_type(4))) unsigned int   uint4v;
typedef __attribute__((ext_vector_type(2))) unsigned int   uint2v;

// ws byte offsets
#define EMB16_OFF ((size_t)0)            // 50000*256 bf16 = 25,600,000 B
#define WXT_OFF   ((size_t)25600000)     // 2*1024*256 bf16 = 1,048,576 B
#define WHT_OFF   ((size_t)26648576)     // 2*1024*256 bf16 = 1,048,576 B
#define HBUF_OFF  ((size_t)27697152)     // primary 262,144 B + mirror 262,144 B
#define WS_NEED   ((size_t)28221440)

__device__ __forceinline__ unsigned short f2bf(float f) {
  unsigned int u = __builtin_bit_cast(unsigned int, f);
  u += 0x7fffu + ((u >> 16) & 1u);            // RNE
  return (unsigned short)(u >> 16);
}
__device__ __forceinline__ float bf2f(unsigned short b) {
  unsigned int u = ((unsigned int)b) << 16;
  return __builtin_bit_cast(float, u);
}
__device__ __forceinline__ float sigf(float x) { return 1.0f / (1.0f + __expf(-x)); }
__device__ __forceinline__ float tanhf_(float x) {
  float t = __expf(-2.0f * fabsf(x));
  float r = (1.0f - t) / (1.0f + t);          // no inf/NaN for any x
  return copysignf(r, x);
}

// ---------------------------------------------------------------------------
// K0: W (f32 [256][1024]) -> Wt (bf16 [1024][256]).  z selects matrix.
__global__ __launch_bounds__(256) void k0_transpose(
    const float* __restrict__ wxf, const float* __restrict__ wxb,
    const float* __restrict__ whf, const float* __restrict__ whb,
    unsigned short* __restrict__ wxt, unsigned short* __restrict__ wht) {
  __shared__ float lds[32][33];
  int mat = blockIdx.z;
  const float* src = (mat == 0) ? wxf : (mat == 1) ? wxb : (mat == 2) ? whf : whb;
  unsigned short* dst = (mat == 0) ? wxt : (mat == 1) ? (wxt + 262144)
                      : (mat == 2) ? wht : (wht + 262144);
  int k0 = blockIdx.x * 32;
  int n0 = blockIdx.y * 32;
  int tx = threadIdx.x & 31, ty = threadIdx.x >> 5;   // ty 0..7
#pragma unroll
  for (int r = 0; r < 4; r++) {
    int k = ty + r * 8;
    lds[k][tx] = src[(size_t)(k0 + k) * 1024 + n0 + tx];
  }
  __syncthreads();
#pragma unroll
  for (int r = 0; r < 4; r++) {
    int n = ty + r * 8;
    dst[(size_t)(n0 + n) * 256 + k0 + tx] = f2bf(lds[tx][n]);
  }
}

// ---------------------------------------------------------------------------
// K0b: emb table f32 -> bf16.  50000*256 = 12.8M elems, 8/thread, 6250 blocks.
__global__ __launch_bounds__(256) void k0b_embcast(
    const float* __restrict__ emb, unsigned short* __restrict__ embbf) {
  size_t i = ((size_t)blockIdx.x * 256 + threadIdx.x) * 8;
  f32x4 v0 = *(const f32x4*)(emb + i);
  f32x4 v1 = *(const f32x4*)(emb + i + 4);
  short8 st;
#pragma unroll
  for (int j = 0; j < 4; j++) {
    st[j]     = (short)f2bf(v0[j]);
    st[4 + j] = (short)f2bf(v1[j]);
  }
  *(short8*)(embbf + i) = st;
}

// ---------------------------------------------------------------------------
// K2: fused zx + recurrence. 32 blocks, 256 thr (4 waves).
// Group gid = bid&7 -> (d = gid>>2, rg = gid&3); member cg = bid>>3.
// (Round-robin dispatch puts a group's 4 members on one XCD; SPEED
//  heuristic only — correctness never depends on placement.)
// Block (d,rg,cg): batch rows rg*16..+16, h-dims cg*64..+64 (all 4 gates).
// Wave w: dims w*16..+16; lane (q,l16): rows q*4..+4, dim w*16+l16;
// gate-major accumulators (cs = gate) -> c-state in registers.
// hbuf primary: [gid][buf][row 16][dim 256] tagged u32 ((t<<16)|bf16), sc0.
// hbuf mirror : same layout at +65536 words, sc1 (deferred publish).
__global__ __launch_bounds__(256, 1) void k2_rnn(
    const int* __restrict__ tokens, const unsigned short* __restrict__ embbf,
    const unsigned short* __restrict__ wxt,   // [2][1024][256] bf16
    const unsigned short* __restrict__ wht,   // [2][1024][256] bf16
    const float* __restrict__ bf_, const float* __restrict__ bb_,
    unsigned int* __restrict__ hbufw) {
  int bx = blockIdx.x;
  int gid = bx & 7;
  int cg  = bx >> 3;
  int d   = gid >> 2;
  int rg  = gid & 3;
  int tid = threadIdx.x;
  int w = tid >> 6, lane = tid & 63, q = lane >> 4, l16 = lane & 15;

  __shared__ unsigned int   tl[16][520];        // tokens, padded rows: 33 KB
  __shared__ unsigned short hl[2][32][16][8];   // h tiles, interleaved: 16 KB

  // ---- token preload (this block's 16 batch rows) ----
  for (int i = tid; i < 8192; i += 256) {
    int row = i >> 9, col = i & 511;
    tl[row][col] = (unsigned int)tokens[(rg * 16 + row) * 512 + col];
  }

  // ---- Wx and Wh B-fragments resident in registers (128+128 regs/lane) ----
  const unsigned short* wxd = wxt + (size_t)d * 262144;
  const unsigned short* whd = wht + (size_t)d * 262144;
  short8 xfr[4][8], bfr[4][8];
#pragma unroll
  for (int cs = 0; cs < 4; cs++) {
    const unsigned short* xp = wxd + (size_t)(cs * 256 + cg * 64 + w * 16 + l16) * 256;
    const unsigned short* wp = whd + (size_t)(cs * 256 + cg * 64 + w * 16 + l16) * 256;
#pragma unroll
    for (int kt = 0; kt < 8; kt++) {
      xfr[cs][kt] = *(const short8*)(xp + kt * 32 + q * 8);
      bfr[cs][kt] = *(const short8*)(wp + kt * 32 + q * 8);
    }
  }

  // zero h LDS tiles (h0 = 0)
  {
    unsigned int* hlw = (unsigned int*)&hl[0][0][0][0];
    for (int i = tid; i < 4096; i += 256) hlw[i] = 0;
  }
  __syncthreads();    // setup barrier (one-time full drain is fine)

  const float* bias = d ? bb_ : bf_;
  float bv[4];
#pragma unroll
  for (int cs = 0; cs < 4; cs++) bv[cs] = bias[cs * 256 + cg * 64 + w * 16 + l16];

  float cst[4] = {0.f, 0.f, 0.f, 0.f};        // c for (row=q*4+r, dim=w*16+l16)
  unsigned int* hb = hbufw + (size_t)gid * 8192;            // primary
  unsigned int* mb = hb + 65536;                            // mirror
  int prow = w * 4 + q;                        // this wave's poll rows
  int ps   = lane & 15;                        // dim quad within 64
  int rcg0 = (cg + 1) & 3, rcg1 = (cg + 2) & 3, rcg2 = (cg + 3) & 3;
  int pbase = prow * 256 + ps * 4;            // words
  int srow  = (q * 4) * 256 + cg * 64 + w * 16 + l16;       // producer base

  int limit = 16;                              // sc0 retry budget (decays)
  unsigned int swm[4] = {0u, 0u, 0u, 0u};      // deferred mirror words

  // prologue: emb row for t=0 (compiler loads; drained before first use)
  short8 eaA[8], eaB[8];
  {
    int ts0 = d ? 511 : 0;
    unsigned int tok0 = tl[l16][ts0];
    const unsigned short* er = embbf + (size_t)tok0 * 256 + q * 8;
#pragma unroll
    for (int kt = 0; kt < 8; ++kt) eaA[kt] = *(const short8*)(er + kt * 32);
  }

  auto step = [&](int t, short8 (&ea)[8], short8 (&en)[8]) {
    int buf = t & 1;
    int tsn = (t < 511) ? (d ? 510 - t : t + 1) : 0;   // next-step token col
    unsigned int tokn = tl[l16][tsn];                  // LDS (lgkm only)
    const unsigned short* ern = embbf + (size_t)tokn * 256 + q * 8;

    // ---- zx tile MFMA from registers (h-independent; overlaps sc0 drain) --
    f32x4 acc[4];
#pragma unroll
    for (int cs = 0; cs < 4; ++cs) acc[cs] = {0.f, 0.f, 0.f, 0.f};
#pragma unroll
    for (int kt = 0; kt < 8; ++kt)
#pragma unroll
      for (int cs = 0; cs < 4; ++cs)
        acc[cs] = __builtin_amdgcn_mfma_f32_16x16x32_bf16(ea[kt], xfr[cs][kt], acc[cs], 0, 0, 0);

    // ---- round 1: [3 poll sc0][8 emb][4 mirror sc1], wait vmcnt(12) ----
    // In-order retirement: vmcnt(12) drains ONLY the 3 poll loads (oldest).
    // emb loads + mirror acks stay in flight until the end-of-step vmcnt(8).
    const unsigned int* q0 = hb + buf * 4096 + pbase + rcg0 * 64;
    const unsigned int* q1 = hb + buf * 4096 + pbase + rcg1 * 64;
    const unsigned int* q2 = hb + buf * 4096 + pbase + rcg2 * 64;
    unsigned int* hwm = mb + buf * 4096 + srow;
    unsigned int tg = (unsigned int)t << 16;
    uint4v r0, r1, r2;
    asm volatile(
        "global_load_dwordx4 %[r0], %[p0], off sc0\n\t"
        "global_load_dwordx4 %[r1], %[p1], off sc0\n\t"
        "global_load_dwordx4 %[r2], %[p2], off sc0\n\t"
        "global_load_dwordx4 %[e0], %[pe], off\n\t"
        "global_load_dwordx4 %[e1], %[pe], off offset:64\n\t"
        "global_load_dwordx4 %[e2], %[pe], off offset:128\n\t"
        "global_load_dwordx4 %[e3], %[pe], off offset:192\n\t"
        "global_load_dwordx4 %[e4], %[pe], off offset:256\n\t"
        "global_load_dwordx4 %[e5], %[pe], off offset:320\n\t"
        "global_load_dwordx4 %[e6], %[pe], off offset:384\n\t"
        "global_load_dwordx4 %[e7], %[pe], off offset:448\n\t"
        "global_store_dword %[m], %[s0], off sc1\n\t"
        "global_store_dword %[m], %[s1], off offset:1024 sc1\n\t"
        "global_store_dword %[m], %[s2], off offset:2048 sc1\n\t"
        "global_store_dword %[m], %[s3], off offset:3072 sc1\n\t"
        "s_waitcnt vmcnt(12)"
        : [r0] "=&v"(r0), [r1] "=&v"(r1), [r2] "=&v"(r2),
          [e0] "=&v"(en[0]), [e1] "=&v"(en[1]), [e2] "=&v"(en[2]), [e3] "=&v"(en[3]),
          [e4] "=&v"(en[4]), [e5] "=&v"(en[5]), [e6] "=&v"(en[6]), [e7] "=&v"(en[7])
        : [p0] "v"(q0), [p1] "v"(q1), [p2] "v"(q2), [pe] "v"(ern),
          [m] "v"(hwm), [s0] "v"(swm[0]), [s1] "v"(swm[1]),
          [s2] "v"(swm[2]), [s3] "v"(swm[3])
        : "memory");
    {
      unsigned int bad = (r0[0] ^ tg) | (r0[1] ^ tg) | (r0[2] ^ tg) | (r0[3] ^ tg)
                       | (r1[0] ^ tg) | (r1[1] ^ tg) | (r1[2] ^ tg) | (r1[3] ^ tg)
                       | (r2[0] ^ tg) | (r2[1] ^ tg) | (r2[2] ^ tg) | (r2[3] ^ tg);
      bool ok = __all((bad & 0xffff0000u) == 0);
      // sc0 retries (budgeted). vmcnt(0) here also drains emb — retry path
      // is already latency-bound, this only simplifies accounting.
      int iters = limit;
      while (!ok && iters-- > 0) {
        asm volatile(
            "global_load_dwordx4 %[r0], %[p0], off sc0\n\t"
            "global_load_dwordx4 %[r1], %[p1], off sc0\n\t"
            "global_load_dwordx4 %[r2], %[p2], off sc0\n\t"
            "s_waitcnt vmcnt(0)"
            : [r0] "=&v"(r0), [r1] "=&v"(r1), [r2] "=&v"(r2)
            : [p0] "v"(q0), [p1] "v"(q1), [p2] "v"(q2)
            : "memory");
        bad = (r0[0] ^ tg) | (r0[1] ^ tg) | (r0[2] ^ tg) | (r0[3] ^ tg)
            | (r1[0] ^ tg) | (r1[1] ^ tg) | (r1[2] ^ tg) | (r1[3] ^ tg)
            | (r2[0] ^ tg) | (r2[1] ^ tg) | (r2[2] ^ tg) | (r2[3] ^ tg);
        ok = __all((bad & 0xffff0000u) == 0);
      }
      if (!ok) {
        limit >>= 1;                           // sticky decay toward sc1-only
        const unsigned int* m0 = q0 + 65536;
        const unsigned int* m1 = q1 + 65536;
        const unsigned int* m2 = q2 + 65536;
        do {
          asm volatile(
              "global_load_dwordx4 %[r0], %[p0], off sc1\n\t"
              "global_load_dwordx4 %[r1], %[p1], off sc1\n\t"
              "global_load_dwordx4 %[r2], %[p2], off sc1\n\t"
              "s_waitcnt vmcnt(0)"
              : [r0] "=&v"(r0), [r1] "=&v"(r1), [r2] "=&v"(r2)
              : [p0] "v"(m0), [p1] "v"(m1), [p2] "v"(m2)
              : "memory");
          bad = (r0[0] ^ tg) | (r0[1] ^ tg) | (r0[2] ^ tg) | (r0[3] ^ tg)
              | (r1[0] ^ tg) | (r1[1] ^ tg) | (r1[2] ^ tg) | (r1[3] ^ tg)
              | (r2[0] ^ tg) | (r2[1] ^ tg) | (r2[2] ^ tg) | (r2[3] ^ tg);
          ok = __all((bad & 0xffff0000u) == 0);
        } while (!ok);
      }
    }

    // deposit packed bf16 into hl[buf] (remote dims; own dims already there)
    {
      int e4 = (ps & 1) * 4, ch2 = ps >> 1;
      uint2v w0, w1, w2;
      w0[0] = __builtin_amdgcn_perm(r0[1], r0[0], 0x05040100u);
      w0[1] = __builtin_amdgcn_perm(r0[3], r0[2], 0x05040100u);
      w1[0] = __builtin_amdgcn_perm(r1[1], r1[0], 0x05040100u);
      w1[1] = __builtin_amdgcn_perm(r1[3], r1[2], 0x05040100u);
      w2[0] = __builtin_amdgcn_perm(r2[1], r2[0], 0x05040100u);
      w2[1] = __builtin_amdgcn_perm(r2[3], r2[2], 0x05040100u);
      *(uint2v*)(&hl[buf][rcg0 * 8 + ch2][prow][e4]) = w0;
      *(uint2v*)(&hl[buf][rcg1 * 8 + ch2][prow][e4]) = w1;
      *(uint2v*)(&hl[buf][rcg2 * 8 + ch2][prow][e4]) = w2;
    }
    // raw barrier: LDS-only drain; sc0/sc1/emb VMEM stays outstanding.
    asm volatile("s_waitcnt lgkmcnt(0)" ::: "memory");
    __builtin_amdgcn_s_barrier();

    // ---- h GEMM: A from LDS tile (conflict-free b128), B from regs ----
#pragma unroll
    for (int kt = 0; kt < 8; ++kt) {
      short8 ha = *(const short8*)(&hl[buf][kt * 4 + q][l16][0]);
#pragma unroll
      for (int cs = 0; cs < 4; ++cs)
        acc[cs] = __builtin_amdgcn_mfma_f32_16x16x32_bf16(ha, bfr[cs][kt], acc[cs], 0, 0, 0);
    }

    // ---- epilogue: per row r: gates, c/h update, LDS write, IMMEDIATE
    //      sc0 store (earlier tag visibility to partners) ----
    unsigned int* hwn = hb + ((buf ^ 1) * 4096) + srow;
    unsigned int wtag = ((unsigned int)(t + 1)) << 16;
    int dim = cg * 64 + w * 16 + l16;
    int chO = dim >> 3, eO = dim & 7;
    unsigned int sw0, sw1, sw2, sw3;
    {
      float iv, fv, gv, ov, hv;
      iv = sigf(acc[0][0] + bv[0]); fv = sigf(acc[1][0] + bv[1]);
      gv = tanhf_(acc[2][0] + bv[2]); ov = sigf(acc[3][0] + bv[3]);
      cst[0] = fv * cst[0] + iv * gv; hv = ov * tanhf_(cst[0]);
      sw0 = wtag | (unsigned int)f2bf(hv);
      hl[buf ^ 1][chO][q * 4 + 0][eO] = (unsigned short)(sw0 & 0xffffu);
      asm volatile("global_store_dword %0, %1, off sc0" :: "v"(hwn), "v"(sw0) : "memory");
      iv = sigf(acc[0][1] + bv[0]); fv = sigf(acc[1][1] + bv[1]);
      gv = tanhf_(acc[2][1] + bv[2]); ov = sigf(acc[3][1] + bv[3]);
      cst[1] = fv * cst[1] + iv * gv; hv = ov * tanhf_(cst[1]);
      sw1 = wtag | (unsigned int)f2bf(hv);
      hl[buf ^ 1][chO][q * 4 + 1][eO] = (unsigned short)(sw1 & 0xffffu);
      asm volatile("global_store_dword %0, %1, off offset:1024 sc0" :: "v"(hwn), "v"(sw1) : "memory");
      iv = sigf(acc[0][2] + bv[0]); fv = sigf(acc[1][2] + bv[1]);
      gv = tanhf_(acc[2][2] + bv[2]); ov = sigf(acc[3][2] + bv[3]);
      cst[2] = fv * cst[2] + iv * gv; hv = ov * tanhf_(cst[2]);
      sw2 = wtag | (unsigned int)f2bf(hv);
      hl[buf ^ 1][chO][q * 4 + 2][eO] = (unsigned short)(sw2 & 0xffffu);
      asm volatile("global_store_dword %0, %1, off offset:2048 sc0" :: "v"(hwn), "v"(sw2) : "memory");
      iv = sigf(acc[0][3] + bv[0]); fv = sigf(acc[1][3] + bv[1]);
      gv = tanhf_(acc[2][3] + bv[2]); ov = sigf(acc[3][3] + bv[3]);
      cst[3] = fv * cst[3] + iv * gv; hv = ov * tanhf_(cst[3]);
      sw3 = wtag | (unsigned int)f2bf(hv);
      hl[buf ^ 1][chO][q * 4 + 3][eO] = (unsigned short)(sw3 & 0xffffu);
      asm volatile("global_store_dword %0, %1, off offset:3072 sc0" :: "v"(hwn), "v"(sw3) : "memory");
    }
    swm[0] = sw0; swm[1] = sw1; swm[2] = sw2; swm[3] = sw3;

    // ---- end-of-step: ensure emb loads (en) retired before next zx MFMA.
    // Outstanding (oldest->newest, fast path): [emb(8)][mirror(4)][primary(4)]
    // -> vmcnt(8) retires emb; mirror + primary acks stay in flight.
    // sched_barrier stops MFMA hoisting past the waitcnt (rule #18).
    asm volatile("s_waitcnt vmcnt(8)" ::: "memory");
    __builtin_amdgcn_sched_barrier(0);
  };

  for (int t2 = 0; t2 < 512; t2 += 2) {
    step(t2,     eaA, eaB);
    step(t2 + 1, eaB, eaA);
  }
}

// ---------------------------------------------------------------------------
// K3: logits + softmax. 64 blocks (one per batch) x 64 threads (one wave).
// Final h_512 (tag 512, buf0) read from the PRIMARY buffers; the k2->k3
// dispatch boundary flushes caches (standard cross-kernel visibility).
__global__ __launch_bounds__(64) void k3_out(
    const unsigned int* __restrict__ hbufw,
    const float* __restrict__ wout, const float* __restrict__ bout,
    float* __restrict__ out) {
  int b = blockIdx.x, tid = threadIdx.x;
  int rg = b >> 4, r = b & 15;
  const unsigned int* hf  = hbufw + (size_t)rg * 8192 + r * 256;           // dir0 buf0
  const unsigned int* hbk = hbufw + 32768 + (size_t)rg * 8192 + r * 256;   // dir1 buf0
  float p[10];
#pragma unroll
  for (int l = 0; l < 10; l++) p[l] = 0.f;
  for (int k = tid; k < 512; k += 64) {
    unsigned int wd = (k < 256) ? hf[k] : hbk[k - 256];
    float f = bf2f((unsigned short)(wd & 0xffffu));
    const float* wr = wout + k * 10;
#pragma unroll
    for (int l = 0; l < 10; l++) p[l] += f * wr[l];
  }
#pragma unroll
  for (int off = 32; off; off >>= 1)
#pragma unroll
    for (int l = 0; l < 10; l++) p[l] += __shfl_down(p[l], off);
  if (tid == 0) {
    float lg[10], m = -1e30f;
#pragma unroll
    for (int l = 0; l < 10; l++) { lg[l] = p[l] + bout[l]; m = fmaxf(m, lg[l]); }
    float sum = 0.f;
#pragma unroll
    for (int l = 0; l < 10; l++) { lg[l] = __expf(lg[l] - m); sum += lg[l]; }
    float inv = 1.0f / sum;
#pragma unroll
    for (int l = 0; l < 10; l++) out[b * 10 + l] = lg[l] * inv;
  }
}

// ---------------------------------------------------------------------------
extern "C" void kernel_launch(void* const* d_in, const int* in_sizes, int n_in,
                              void* d_out, int out_size, void* d_ws, size_t ws_size,
                              hipStream_t stream) {
  const int*   tokens = (const int*)d_in[0];
  const float* emb    = (const float*)d_in[1];
  const float* wxf    = (const float*)d_in[2];
  const float* whf    = (const float*)d_in[3];
  const float* bf_    = (const float*)d_in[4];
  const float* wxb    = (const float*)d_in[5];
  const float* whb    = (const float*)d_in[6];
  const float* bb_    = (const float*)d_in[7];
  const float* wout   = (const float*)d_in[8];
  const float* bout   = (const float*)d_in[9];
  float* out = (float*)d_out;

  char* ws = (char*)d_ws;
  unsigned short* embbf = (unsigned short*)(ws + EMB16_OFF);
  unsigned short* wxt   = (unsigned short*)(ws + WXT_OFF);
  unsigned short* wht   = (unsigned short*)(ws + WHT_OFF);
  unsigned int*   hbufw = (unsigned int*)(ws + HBUF_OFF);
  (void)ws_size; (void)in_sizes; (void)n_in; (void)out_size;   // needs WS_NEED bytes

  // zero h0 (tag 0 == step 0) in primary AND mirror buffers
  hipMemsetAsync(ws + HBUF_OFF, 0, 524288, stream);

  k0_transpose<<<dim3(8, 32, 4), 256, 0, stream>>>(wxf, wxb, whf, whb, wxt, wht);
  k0b_embcast<<<6250, 256, 0, stream>>>(emb, embbf);
  k2_rnn<<<32, 256, 0, stream>>>(tokens, embbf, wxt, wht, bf_, bb_, hbufw);
  k3_out<<<64, 64, 0, stream>>>(hbufw, wout, bout, out);
}

// Round 8
// 1428.156 us; speedup vs baseline: 1.1052x; 1.0739x over previous
//
#include <hip/hip_runtime.h>
#include <stdint.h>
#include <stddef.h>

// ---------------------------------------------------------------------------
// TextRNN: embed -> BiLSTM(512 steps) -> linear -> softmax   (MI355X gfx950)
//
// R10 (delta vs R7/R9): RUNTIME XCD-DISCOVERY GROUPING.
// Evidence: sc1+15p=3.6us/step, sc1+3p=3.6, sc0+3p=2.6-2.8 — only cache
// scope ever moved the step time, and tag visibility measures ~1.5-2us
// (MALL-class, not shared-L2-class). Theory: dispatch is chunked, so the
// static groups {g,g+8,g+16,g+24} spanned 4 XCDs and every sc0 exchange
// was a cross-XCD dirty-line resolution.
// Fix: each block publishes HW_REG_XCC_ID via sc1; all blocks read all 32
// descs, sort keys (xcc<<8|bid), chunk ranks into groups of 4 -> perfect
// same-XCD groups under chunked OR round-robin dispatch. Weird placements
// give mixed groups that run the proven sc1 fallback (dual-publish kept ->
// hang-proof by construction; placement affects SPEED only).
// Main loop = R7's measured-best structure verbatim.
// K0 : transpose/cast Wx,Wh -> bf16 [1024][256]
// K0b: cast emb table f32 -> bf16
// K2 : fused zx + recurrence (32 blocks = 8 groups x 4 cg, 256 thr)
// K3 : logits + softmax (reads primary; dispatch boundary flushes)
// ---------------------------------------------------------------------------

typedef __attribute__((ext_vector_type(8))) short   short8;
typedef __attribute__((ext_vector_type(4))) float   f32x4;
typedef __attribute__((ext_vector_type(4))) unsigned short ushort4v;
typedef __attribute__((ext_vector_type(4))) unsigned int   uint4v;
typedef __attribute__((ext_vector_type(2))) unsigned int   uint2v;

// ws byte offsets
#define EMB16_OFF ((size_t)0)            // 50000*256 bf16 = 25,600,000 B
#define WXT_OFF   ((size_t)25600000)     // 2*1024*256 bf16 = 1,048,576 B
#define WHT_OFF   ((size_t)26648576)     // 2*1024*256 bf16 = 1,048,576 B
#define HBUF_OFF  ((size_t)27697152)     // primary 262144 + mirror 262144 + desc 128
#define WS_NEED   ((size_t)28221568)

__device__ __forceinline__ unsigned short f2bf(float f) {
  unsigned int u = __builtin_bit_cast(unsigned int, f);
  u += 0x7fffu + ((u >> 16) & 1u);            // RNE
  return (unsigned short)(u >> 16);
}
__device__ __forceinline__ float bf2f(unsigned short b) {
  unsigned int u = ((unsigned int)b) << 16;
  return __builtin_bit_cast(float, u);
}
__device__ __forceinline__ float sigf(float x) { return 1.0f / (1.0f + __expf(-x)); }
__device__ __forceinline__ float tanhf_(float x) {
  float t = __expf(-2.0f * fabsf(x));
  float r = (1.0f - t) / (1.0f + t);          // no inf/NaN for any x
  return copysignf(r, x);
}

// ---------------------------------------------------------------------------
// K0: W (f32 [256][1024]) -> Wt (bf16 [1024][256]).  z selects matrix.
__global__ __launch_bounds__(256) void k0_transpose(
    const float* __restrict__ wxf, const float* __restrict__ wxb,
    const float* __restrict__ whf, const float* __restrict__ whb,
    unsigned short* __restrict__ wxt, unsigned short* __restrict__ wht) {
  __shared__ float lds[32][33];
  int mat = blockIdx.z;
  const float* src = (mat == 0) ? wxf : (mat == 1) ? wxb : (mat == 2) ? whf : whb;
  unsigned short* dst = (mat == 0) ? wxt : (mat == 1) ? (wxt + 262144)
                      : (mat == 2) ? wht : (wht + 262144);
  int k0 = blockIdx.x * 32;
  int n0 = blockIdx.y * 32;
  int tx = threadIdx.x & 31, ty = threadIdx.x >> 5;   // ty 0..7
#pragma unroll
  for (int r = 0; r < 4; r++) {
    int k = ty + r * 8;
    lds[k][tx] = src[(size_t)(k0 + k) * 1024 + n0 + tx];
  }
  __syncthreads();
#pragma unroll
  for (int r = 0; r < 4; r++) {
    int n = ty + r * 8;
    dst[(size_t)(n0 + n) * 256 + k0 + tx] = f2bf(lds[tx][n]);
  }
}

// ---------------------------------------------------------------------------
// K0b: emb table f32 -> bf16.  50000*256 = 12.8M elems, 8/thread, 6250 blocks.
__global__ __launch_bounds__(256) void k0b_embcast(
    const float* __restrict__ emb, unsigned short* __restrict__ embbf) {
  size_t i = ((size_t)blockIdx.x * 256 + threadIdx.x) * 8;
  f32x4 v0 = *(const f32x4*)(emb + i);
  f32x4 v1 = *(const f32x4*)(emb + i + 4);
  short8 st;
#pragma unroll
  for (int j = 0; j < 4; j++) {
    st[j]     = (short)f2bf(v0[j]);
    st[4 + j] = (short)f2bf(v1[j]);
  }
  *(short8*)(embbf + i) = st;
}

// ---------------------------------------------------------------------------
// K2: fused zx + recurrence. 32 blocks, 256 thr (4 waves).
// DYNAMIC grouping: rank = position of key (xcc<<8|bid) in sorted order of
// all 32 keys; group g = rank>>2 -> (d = g>>2, rg = g&3); member cg = rank&3.
// Block (d,rg,cg): batch rows rg*16..+16, h-dims cg*64..+64 (all 4 gates).
// Wave w: dims w*16..+16; lane (q,l16): rows q*4..+4, dim w*16+l16;
// gate-major accumulators (cs = gate) -> c-state in registers.
// hbuf primary: [g][buf][row 16][dim 256] tagged u32 ((t<<16)|bf16), sc0.
// hbuf mirror : same layout at +65536 words, sc1. desc: +131072 words.
__global__ __launch_bounds__(256, 1) void k2_rnn(
    const int* __restrict__ tokens, const unsigned short* __restrict__ embbf,
    const unsigned short* __restrict__ wxt,   // [2][1024][256] bf16
    const unsigned short* __restrict__ wht,   // [2][1024][256] bf16
    const float* __restrict__ bf_, const float* __restrict__ bb_,
    unsigned int* __restrict__ hbufw) {
  int bx = blockIdx.x;
  int tid = threadIdx.x;
  int w = tid >> 6, lane = tid & 63, q = lane >> 4, l16 = lane & 15;

  // ---- XCD discovery & dynamic group assignment ----
  unsigned int* desc = hbufw + 131072;
  {
    unsigned int xcc = __builtin_amdgcn_s_getreg((31 << 11) | 20) & 0xffu;  // HW_REG_XCC_ID
    if (tid == 0) {
      unsigned int v = 0x100u | xcc;
      asm volatile("global_store_dword %0, %1, off sc1"
                   :: "v"(desc + bx), "v"(v) : "memory");
    }
  }
  int g, cg;
  {
    const unsigned int* dp = desc + (lane & 31);
    unsigned int dv;
    while (true) {
      asm volatile("global_load_dword %0, %1, off sc1\n\ts_waitcnt vmcnt(0)"
                   : "=&v"(dv) : "v"(dp) : "memory");
      if (__all((dv & 0x100u) != 0u)) break;
    }
    // key: xcc major, bid minor -> sorted ranks chunk same-XCD blocks into 4s
    unsigned int key = ((dv & 0xffu) << 8) | (unsigned int)(lane & 31);
    int rank = 0;
#pragma unroll
    for (int j = 0; j < 32; ++j) {
      unsigned int kj = __shfl(key, j);
      rank += (kj < key) ? 1 : 0;
    }
    int myrank = __shfl(rank, bx);   // our block's rank (bx < 32)
    g  = myrank >> 2;
    cg = myrank & 3;
  }
  int d  = g >> 2;
  int rg = g & 3;

  __shared__ unsigned short wx2[32][256][8];    // Wx slice, interleaved: 131072 B
  __shared__ unsigned short hl[2][32][16][8];   // h tiles, interleaved:   16384 B

  // ---- preload Wx slice (block cols: gate*256 + cg*64 + dl) into wx2 ----
  const unsigned short* wxd = wxt + (size_t)d * 262144;
  for (int it = 0; it < 32; ++it) {
    int idx = it * 256 + tid;                 // 8192 16B-chunks
    int cl = idx & 255, ch = idx >> 8;        // cl = cs*64+dl, ch = kt*4+q
    int gcol = (cl >> 6) * 256 + cg * 64 + (cl & 63);
    *(short8*)(&wx2[ch][cl][0]) = *(const short8*)(wxd + (size_t)gcol * 256 + ch * 8);
  }

  // ---- Wh B-fragments resident in registers (128 regs/lane) ----
  const unsigned short* whd = wht + (size_t)d * 262144;
  short8 bfr[4][8];
#pragma unroll
  for (int cs = 0; cs < 4; cs++) {
    const unsigned short* wp = whd + (size_t)(cs * 256 + cg * 64 + w * 16 + l16) * 256;
#pragma unroll
    for (int kt = 0; kt < 8; kt++)
      bfr[cs][kt] = *(const short8*)(wp + kt * 32 + q * 8);
  }

  // zero h LDS tiles (h0 = 0)
  {
    unsigned int* hlw = (unsigned int*)&hl[0][0][0][0];
    for (int i = tid; i < 4096; i += 256) hlw[i] = 0;
  }
  __syncthreads();

  const float* bias = d ? bb_ : bf_;
  float bv[4];
#pragma unroll
  for (int cs = 0; cs < 4; cs++) bv[cs] = bias[cs * 256 + cg * 64 + w * 16 + l16];

  float cst[4] = {0.f, 0.f, 0.f, 0.f};        // c for (row=q*4+r, dim=w*16+l16)
  unsigned int* hb = hbufw + (size_t)g * 8192;              // primary
  int prow = w * 4 + q;                        // this wave's poll rows
  int ps   = lane & 15;                        // dim quad within 64
  int rcg0 = (cg + 1) & 3, rcg1 = (cg + 2) & 3, rcg2 = (cg + 3) & 3;
  int pbase = prow * 256 + ps * 4;            // words
  int srow  = (q * 4) * 256 + cg * 64 + w * 16 + l16;       // producer base
  const int* tokrow = tokens + (rg * 16 + l16) * 512;

  int limit = 16;                              // adaptive sc0 poll budget

  // prologue: emb row for t=0
  short8 ea[8];
  {
    int ts0 = d ? 511 : 0;
    int tok0 = tokrow[ts0];
    const unsigned short* er = embbf + (size_t)tok0 * 256 + q * 8;
#pragma unroll
    for (int kt = 0; kt < 8; ++kt) ea[kt] = *(const short8*)(er + kt * 32);
  }

  for (int t = 0; t < 512; ++t) {
    int buf = t & 1;
    int tsn = (t < 511) ? (d ? 510 - t : t + 1) : 0;   // next-step token col
    int tok_n = tokrow[tsn];

    // ---- zx tile MFMA (uses prefetched ea; h-independent; overlaps the
    //      propagation of our un-drained stores from the previous step) ----
    f32x4 acc[4];
#pragma unroll
    for (int cs = 0; cs < 4; ++cs) acc[cs] = {0.f, 0.f, 0.f, 0.f};
#pragma unroll
    for (int kt = 0; kt < 8; ++kt) {
#pragma unroll
      for (int cs = 0; cs < 4; ++cs) {
        short8 xb = *(const short8*)(&wx2[kt * 4 + q][cs * 64 + w * 16 + l16][0]);
        acc[cs] = __builtin_amdgcn_mfma_f32_16x16x32_bf16(ea[kt], xb, acc[cs], 0, 0, 0);
      }
    }

    // ---- poll: this wave's 4 rows x 3 remote producers.
    // Phase 1: sc0 primary (fast iff group co-resident on one XCD), up to
    // `limit` rounds. Phase 2 (guaranteed): sc1 mirror — always written by
    // producers, correct under any placement. First round's vmcnt(0) also
    // drains our 8 un-drained stores from the previous step.
    const unsigned int* q0 = hb + buf * 4096 + pbase + rcg0 * 64;
    const unsigned int* q1 = hb + buf * 4096 + pbase + rcg1 * 64;
    const unsigned int* q2 = hb + buf * 4096 + pbase + rcg2 * 64;
    unsigned int tg = (unsigned int)t << 16;
    uint4v r0, r1, r2;
    bool got = false;
    for (int it = 0; it < limit; ++it) {
      asm volatile(
          "global_load_dwordx4 %[r0], %[p0], off sc0\n\t"
          "global_load_dwordx4 %[r1], %[p1], off sc0\n\t"
          "global_load_dwordx4 %[r2], %[p2], off sc0\n\t"
          "s_waitcnt vmcnt(0)"
          : [r0] "=&v"(r0), [r1] "=&v"(r1), [r2] "=&v"(r2)
          : [p0] "v"(q0), [p1] "v"(q1), [p2] "v"(q2)
          : "memory");
      unsigned int bad = (r0[0] ^ tg) | (r0[1] ^ tg) | (r0[2] ^ tg) | (r0[3] ^ tg)
                       | (r1[0] ^ tg) | (r1[1] ^ tg) | (r1[2] ^ tg) | (r1[3] ^ tg)
                       | (r2[0] ^ tg) | (r2[1] ^ tg) | (r2[2] ^ tg) | (r2[3] ^ tg);
      if (__all((bad & 0xffff0000u) == 0)) { got = true; break; }
    }
    if (!got) {
      limit >>= 1;                             // sticky decay toward sc1-only
      const unsigned int* m0 = q0 + 65536;
      const unsigned int* m1 = q1 + 65536;
      const unsigned int* m2 = q2 + 65536;
      while (true) {
        asm volatile(
            "global_load_dwordx4 %[r0], %[p0], off sc1\n\t"
            "global_load_dwordx4 %[r1], %[p1], off sc1\n\t"
            "global_load_dwordx4 %[r2], %[p2], off sc1\n\t"
            "s_waitcnt vmcnt(0)"
            : [r0] "=&v"(r0), [r1] "=&v"(r1), [r2] "=&v"(r2)
            : [p0] "v"(m0), [p1] "v"(m1), [p2] "v"(m2)
            : "memory");
        unsigned int bad = (r0[0] ^ tg) | (r0[1] ^ tg) | (r0[2] ^ tg) | (r0[3] ^ tg)
                         | (r1[0] ^ tg) | (r1[1] ^ tg) | (r1[2] ^ tg) | (r1[3] ^ tg)
                         | (r2[0] ^ tg) | (r2[1] ^ tg) | (r2[2] ^ tg) | (r2[3] ^ tg);
        if (__all((bad & 0xffff0000u) == 0)) break;
      }
    }

    // ---- emb prefetch for t+1 (flies during h-GEMM + epilogue) ----
    short8 ean[8];
    {
      const unsigned short* ern = embbf + (size_t)tok_n * 256 + q * 8;
#pragma unroll
      for (int kt = 0; kt < 8; ++kt) ean[kt] = *(const short8*)(ern + kt * 32);
    }

    // deposit packed bf16 into hl[buf] (remote dims; own dims already there)
    {
      int e4 = (ps & 1) * 4, ch2 = ps >> 1;
      uint2v w0, w1, w2;
      w0[0] = __builtin_amdgcn_perm(r0[1], r0[0], 0x05040100u);
      w0[1] = __builtin_amdgcn_perm(r0[3], r0[2], 0x05040100u);
      w1[0] = __builtin_amdgcn_perm(r1[1], r1[0], 0x05040100u);
      w1[1] = __builtin_amdgcn_perm(r1[3], r1[2], 0x05040100u);
      w2[0] = __builtin_amdgcn_perm(r2[1], r2[0], 0x05040100u);
      w2[1] = __builtin_amdgcn_perm(r2[3], r2[2], 0x05040100u);
      *(uint2v*)(&hl[buf][rcg0 * 8 + ch2][prow][e4]) = w0;
      *(uint2v*)(&hl[buf][rcg1 * 8 + ch2][prow][e4]) = w1;
      *(uint2v*)(&hl[buf][rcg2 * 8 + ch2][prow][e4]) = w2;
    }
    __syncthreads();   // hl[buf] complete; also publishes prev epilogue writes

    // ---- h GEMM: A from LDS tile (conflict-free b128), B from regs ----
#pragma unroll
    for (int kt = 0; kt < 8; ++kt) {
      short8 ha = *(const short8*)(&hl[buf][kt * 4 + q][l16][0]);
#pragma unroll
      for (int cs = 0; cs < 4; ++cs)
        acc[cs] = __builtin_amdgcn_mfma_f32_16x16x32_bf16(ha, bfr[cs][kt], acc[cs], 0, 0, 0);
    }

    // ---- epilogue: gates, c/h update, LDS own-dims, dual tagged stores ----
    unsigned int* hwn = hb + ((buf ^ 1) * 4096) + srow;
    unsigned int wtag = ((unsigned int)(t + 1)) << 16;
    int dim = cg * 64 + w * 16 + l16;
    int chO = dim >> 3, eO = dim & 7;
    unsigned int sw[4];
#pragma unroll
    for (int r = 0; r < 4; ++r) {
      float iv = sigf(acc[0][r] + bv[0]);
      float fv = sigf(acc[1][r] + bv[1]);
      float gv = tanhf_(acc[2][r] + bv[2]);
      float ov = sigf(acc[3][r] + bv[3]);
      cst[r] = fv * cst[r] + iv * gv;
      float hv = ov * tanhf_(cst[r]);
      unsigned short h16 = f2bf(hv);
      sw[r] = wtag | (unsigned int)h16;
      hl[buf ^ 1][chO][q * 4 + r][eO] = h16;
    }
    // dual-publish: sc0 primary (fast path) + sc1 mirror (guaranteed path).
    // NO drain: next poll's vmcnt(0) drains them, overlapped with zx MFMA.
    {
      unsigned int* hwm = hwn + 65536;
      asm volatile(
          "global_store_dword %[p], %[v0], off sc0\n\t"
          "global_store_dword %[p], %[v1], off offset:1024 sc0\n\t"
          "global_store_dword %[p], %[v2], off offset:2048 sc0\n\t"
          "global_store_dword %[p], %[v3], off offset:3072 sc0\n\t"
          "global_store_dword %[m], %[v0], off sc1\n\t"
          "global_store_dword %[m], %[v1], off offset:1024 sc1\n\t"
          "global_store_dword %[m], %[v2], off offset:2048 sc1\n\t"
          "global_store_dword %[m], %[v3], off offset:3072 sc1"
          :: [p] "v"(hwn), [m] "v"(hwm), [v0] "v"(sw[0]), [v1] "v"(sw[1]),
             [v2] "v"(sw[2]), [v3] "v"(sw[3])
          : "memory");
    }

    // rotate emb prefetch
#pragma unroll
    for (int kt = 0; kt < 8; ++kt) ea[kt] = ean[kt];
  }
}

// ---------------------------------------------------------------------------
// K3: logits + softmax. 64 blocks (one per batch) x 64 threads (one wave).
// Final h_512 (tag 512, buf0) read from the PRIMARY buffers; the k2->k3
// dispatch boundary flushes caches (standard cross-kernel visibility).
__global__ __launch_bounds__(64) void k3_out(
    const unsigned int* __restrict__ hbufw,
    const float* __restrict__ wout, const float* __restrict__ bout,
    float* __restrict__ out) {
  int b = blockIdx.x, tid = threadIdx.x;
  int rg = b >> 4, r = b & 15;
  const unsigned int* hf  = hbufw + (size_t)rg * 8192 + r * 256;           // dir0 buf0
  const unsigned int* hbk = hbufw + 32768 + (size_t)rg * 8192 + r * 256;   // dir1 buf0
  float p[10];
#pragma unroll
  for (int l = 0; l < 10; l++) p[l] = 0.f;
  for (int k = tid; k < 512; k += 64) {
    unsigned int wd = (k < 256) ? hf[k] : hbk[k - 256];
    float f = bf2f((unsigned short)(wd & 0xffffu));
    const float* wr = wout + k * 10;
#pragma unroll
    for (int l = 0; l < 10; l++) p[l] += f * wr[l];
  }
#pragma unroll
  for (int off = 32; off; off >>= 1)
#pragma unroll
    for (int l = 0; l < 10; l++) p[l] += __shfl_down(p[l], off);
  if (tid == 0) {
    float lg[10], m = -1e30f;
#pragma unroll
    for (int l = 0; l < 10; l++) { lg[l] = p[l] + bout[l]; m = fmaxf(m, lg[l]); }
    float sum = 0.f;
#pragma unroll
    for (int l = 0; l < 10; l++) { lg[l] = __expf(lg[l] - m); sum += lg[l]; }
    float inv = 1.0f / sum;
#pragma unroll
    for (int l = 0; l < 10; l++) out[b * 10 + l] = lg[l] * inv;
  }
}

// ---------------------------------------------------------------------------
extern "C" void kernel_launch(void* const* d_in, const int* in_sizes, int n_in,
                              void* d_out, int out_size, void* d_ws, size_t ws_size,
                              hipStream_t stream) {
  const int*   tokens = (const int*)d_in[0];
  const float* emb    = (const float*)d_in[1];
  const float* wxf    = (const float*)d_in[2];
  const float* whf    = (const float*)d_in[3];
  const float* bf_    = (const float*)d_in[4];
  const float* wxb    = (const float*)d_in[5];
  const float* whb    = (const float*)d_in[6];
  const float* bb_    = (const float*)d_in[7];
  const float* wout   = (const float*)d_in[8];
  const float* bout   = (const float*)d_in[9];
  float* out = (float*)d_out;

  char* ws = (char*)d_ws;
  unsigned short* embbf = (unsigned short*)(ws + EMB16_OFF);
  unsigned short* wxt   = (unsigned short*)(ws + WXT_OFF);
  unsigned short* wht   = (unsigned short*)(ws + WHT_OFF);
  unsigned int*   hbufw = (unsigned int*)(ws + HBUF_OFF);
  (void)ws_size; (void)in_sizes; (void)n_in; (void)out_size;   // needs WS_NEED bytes

  // zero h0 (tag 0 == step 0) in primary, mirror, and desc area
  hipMemsetAsync(ws + HBUF_OFF, 0, 524416, stream);

  k0_transpose<<<dim3(8, 32, 4), 256, 0, stream>>>(wxf, wxb, whf, whb, wxt, wht);
  k0b_embcast<<<6250, 256, 0, stream>>>(emb, embbf);
  k2_rnn<<<32, 256, 0, stream>>>(tokens, embbf, wxt, wht, bf_, bb_, hbufw);
  k3_out<<<64, 64, 0, stream>>>(hbufw, wout, bout, out);
}

// Round 9
// 1377.909 us; speedup vs baseline: 1.1455x; 1.0365x over previous
//
#include <hip/hip_runtime.h>
#include <stdint.h>
#include <stddef.h>

// ---------------------------------------------------------------------------
// TextRNN: embed -> BiLSTM(512 steps) -> linear -> softmax   (MI355X gfx950)
//
// R11 (delta vs R10): CONTENTION-REDUCTION on the h-exchange.
// Measured: same-XCD sc0 exchange = ~2.3us/step, ~15-17 poll rounds (VALU
// arithmetic). Theory: polled lines ping-pong — 3 CUs x 4 waves hammer the
// producer's lines with vmcnt(0) loads, delaying the producer's write
// visibility. Changes:
//  1. ONE polling wave per producer (wave w in {0,1,2} polls producer
//     (cg+1+w)'s whole 16x64 tile; wave 3 skips) -> 3x fewer line readers.
//  2. s_sleep(2) backoff between failed rounds -> L2 port relief.
//  3. Producer drains its 4 sc0 primaries (vmcnt(0)) BEFORE issuing sc1
//     mirrors -> earliest possible flush of the tag into L2.
// Retained: runtime XCD-discovery grouping (same-XCD groups guaranteed),
// dual-publish sc0-primary/sc1-mirror with budgeted fallback (hang-proof
// under any placement), R7 main-loop skeleton.
// K0 : transpose/cast Wx,Wh -> bf16 [1024][256]
// K0b: cast emb table f32 -> bf16
// K2 : fused zx + recurrence (32 blocks = 8 groups x 4 cg, 256 thr)
// K3 : logits + softmax (reads primary; dispatch boundary flushes)
// ---------------------------------------------------------------------------

typedef __attribute__((ext_vector_type(8))) short   short8;
typedef __attribute__((ext_vector_type(4))) float   f32x4;
typedef __attribute__((ext_vector_type(4))) unsigned short ushort4v;
typedef __attribute__((ext_vector_type(4))) unsigned int   uint4v;
typedef __attribute__((ext_vector_type(2))) unsigned int   uint2v;

// ws byte offsets
#define EMB16_OFF ((size_t)0)            // 50000*256 bf16 = 25,600,000 B
#define WXT_OFF   ((size_t)25600000)     // 2*1024*256 bf16 = 1,048,576 B
#define WHT_OFF   ((size_t)26648576)     // 2*1024*256 bf16 = 1,048,576 B
#define HBUF_OFF  ((size_t)27697152)     // primary 262144 + mirror 262144 + desc 128
#define WS_NEED   ((size_t)28221568)

__device__ __forceinline__ unsigned short f2bf(float f) {
  unsigned int u = __builtin_bit_cast(unsigned int, f);
  u += 0x7fffu + ((u >> 16) & 1u);            // RNE
  return (unsigned short)(u >> 16);
}
__device__ __forceinline__ float bf2f(unsigned short b) {
  unsigned int u = ((unsigned int)b) << 16;
  return __builtin_bit_cast(float, u);
}
__device__ __forceinline__ float sigf(float x) { return 1.0f / (1.0f + __expf(-x)); }
__device__ __forceinline__ float tanhf_(float x) {
  float t = __expf(-2.0f * fabsf(x));
  float r = (1.0f - t) / (1.0f + t);          // no inf/NaN for any x
  return copysignf(r, x);
}

// ---------------------------------------------------------------------------
// K0: W (f32 [256][1024]) -> Wt (bf16 [1024][256]).  z selects matrix.
__global__ __launch_bounds__(256) void k0_transpose(
    const float* __restrict__ wxf, const float* __restrict__ wxb,
    const float* __restrict__ whf, const float* __restrict__ whb,
    unsigned short* __restrict__ wxt, unsigned short* __restrict__ wht) {
  __shared__ float lds[32][33];
  int mat = blockIdx.z;
  const float* src = (mat == 0) ? wxf : (mat == 1) ? wxb : (mat == 2) ? whf : whb;
  unsigned short* dst = (mat == 0) ? wxt : (mat == 1) ? (wxt + 262144)
                      : (mat == 2) ? wht : (wht + 262144);
  int k0 = blockIdx.x * 32;
  int n0 = blockIdx.y * 32;
  int tx = threadIdx.x & 31, ty = threadIdx.x >> 5;   // ty 0..7
#pragma unroll
  for (int r = 0; r < 4; r++) {
    int k = ty + r * 8;
    lds[k][tx] = src[(size_t)(k0 + k) * 1024 + n0 + tx];
  }
  __syncthreads();
#pragma unroll
  for (int r = 0; r < 4; r++) {
    int n = ty + r * 8;
    dst[(size_t)(n0 + n) * 256 + k0 + tx] = f2bf(lds[tx][n]);
  }
}

// ---------------------------------------------------------------------------
// K0b: emb table f32 -> bf16.  50000*256 = 12.8M elems, 8/thread, 6250 blocks.
__global__ __launch_bounds__(256) void k0b_embcast(
    const float* __restrict__ emb, unsigned short* __restrict__ embbf) {
  size_t i = ((size_t)blockIdx.x * 256 + threadIdx.x) * 8;
  f32x4 v0 = *(const f32x4*)(emb + i);
  f32x4 v1 = *(const f32x4*)(emb + i + 4);
  short8 st;
#pragma unroll
  for (int j = 0; j < 4; j++) {
    st[j]     = (short)f2bf(v0[j]);
    st[4 + j] = (short)f2bf(v1[j]);
  }
  *(short8*)(embbf + i) = st;
}

// ---------------------------------------------------------------------------
// K2: fused zx + recurrence. 32 blocks, 256 thr (4 waves).
// DYNAMIC grouping (R10): rank of key (xcc<<8|bid) in sorted order of all
// 32 keys; group g = rank>>2 -> (d = g>>2, rg = g&3); member cg = rank&3.
// Block (d,rg,cg): batch rows rg*16..+16, h-dims cg*64..+64 (all 4 gates).
// Wave w: dims w*16..+16; lane (q,l16): rows q*4..+4, dim w*16+l16;
// gate-major accumulators (cs = gate) -> c-state in registers.
// hbuf primary: [g][buf][row 16][dim 256] tagged u32 ((t<<16)|bf16), sc0.
// hbuf mirror : same layout at +65536 words, sc1. desc: +131072 words.
// POLL (R11): wave w<3 polls producer p=(cg+1+w)&3's full tile; lane l:
// row = l>>2, 16-dim quad q4 = l&3 -> 4 dwordx4 at row*1024B + p*256B +
// q4*64B. Deposits 16 bf16 into hl chunks p*8+q4*2, +1.
__global__ __launch_bounds__(256, 1) void k2_rnn(
    const int* __restrict__ tokens, const unsigned short* __restrict__ embbf,
    const unsigned short* __restrict__ wxt,   // [2][1024][256] bf16
    const unsigned short* __restrict__ wht,   // [2][1024][256] bf16
    const float* __restrict__ bf_, const float* __restrict__ bb_,
    unsigned int* __restrict__ hbufw) {
  int bx = blockIdx.x;
  int tid = threadIdx.x;
  int w = tid >> 6, lane = tid & 63, q = lane >> 4, l16 = lane & 15;

  // ---- XCD discovery & dynamic group assignment ----
  unsigned int* desc = hbufw + 131072;
  {
    unsigned int xcc = __builtin_amdgcn_s_getreg((31 << 11) | 20) & 0xffu;  // HW_REG_XCC_ID
    if (tid == 0) {
      unsigned int v = 0x100u | xcc;
      asm volatile("global_store_dword %0, %1, off sc1"
                   :: "v"(desc + bx), "v"(v) : "memory");
    }
  }
  int g, cg;
  {
    const unsigned int* dp = desc + (lane & 31);
    unsigned int dv;
    while (true) {
      asm volatile("global_load_dword %0, %1, off sc1\n\ts_waitcnt vmcnt(0)"
                   : "=&v"(dv) : "v"(dp) : "memory");
      if (__all((dv & 0x100u) != 0u)) break;
    }
    unsigned int key = ((dv & 0xffu) << 8) | (unsigned int)(lane & 31);
    int rank = 0;
#pragma unroll
    for (int j = 0; j < 32; ++j) {
      unsigned int kj = __shfl(key, j);
      rank += (kj < key) ? 1 : 0;
    }
    int myrank = __shfl(rank, bx);   // our block's rank (bx < 32)
    g  = myrank >> 2;
    cg = myrank & 3;
  }
  int d  = g >> 2;
  int rg = g & 3;

  __shared__ unsigned short wx2[32][256][8];    // Wx slice, interleaved: 131072 B
  __shared__ unsigned short hl[2][32][16][8];   // h tiles, interleaved:   16384 B

  // ---- preload Wx slice (block cols: gate*256 + cg*64 + dl) into wx2 ----
  const unsigned short* wxd = wxt + (size_t)d * 262144;
  for (int it = 0; it < 32; ++it) {
    int idx = it * 256 + tid;                 // 8192 16B-chunks
    int cl = idx & 255, ch = idx >> 8;        // cl = cs*64+dl, ch = kt*4+q
    int gcol = (cl >> 6) * 256 + cg * 64 + (cl & 63);
    *(short8*)(&wx2[ch][cl][0]) = *(const short8*)(wxd + (size_t)gcol * 256 + ch * 8);
  }

  // ---- Wh B-fragments resident in registers (128 regs/lane) ----
  const unsigned short* whd = wht + (size_t)d * 262144;
  short8 bfr[4][8];
#pragma unroll
  for (int cs = 0; cs < 4; cs++) {
    const unsigned short* wp = whd + (size_t)(cs * 256 + cg * 64 + w * 16 + l16) * 256;
#pragma unroll
    for (int kt = 0; kt < 8; kt++)
      bfr[cs][kt] = *(const short8*)(wp + kt * 32 + q * 8);
  }

  // zero h LDS tiles (h0 = 0)
  {
    unsigned int* hlw = (unsigned int*)&hl[0][0][0][0];
    for (int i = tid; i < 4096; i += 256) hlw[i] = 0;
  }
  __syncthreads();

  const float* bias = d ? bb_ : bf_;
  float bv[4];
#pragma unroll
  for (int cs = 0; cs < 4; cs++) bv[cs] = bias[cs * 256 + cg * 64 + w * 16 + l16];

  float cst[4] = {0.f, 0.f, 0.f, 0.f};        // c for (row=q*4+r, dim=w*16+l16)
  unsigned int* hb = hbufw + (size_t)g * 8192;              // primary
  int srow  = (q * 4) * 256 + cg * 64 + w * 16 + l16;       // producer base
  const int* tokrow = tokens + (rg * 16 + l16) * 512;

  // R11 poll geometry (waves 0..2 only)
  int p_w   = (cg + 1 + w) & 3;               // this wave's producer
  int prow2 = lane >> 2;                      // row 0..15
  int pq4   = lane & 3;                       // 16-dim quad within 64
  int pbase2 = prow2 * 256 + p_w * 64 + pq4 * 16;   // word offset

  int limit = 16;                              // adaptive sc0 poll budget

  // prologue: emb row for t=0
  short8 ea[8];
  {
    int ts0 = d ? 511 : 0;
    int tok0 = tokrow[ts0];
    const unsigned short* er = embbf + (size_t)tok0 * 256 + q * 8;
#pragma unroll
    for (int kt = 0; kt < 8; ++kt) ea[kt] = *(const short8*)(er + kt * 32);
  }

  for (int t = 0; t < 512; ++t) {
    int buf = t & 1;
    int tsn = (t < 511) ? (d ? 510 - t : t + 1) : 0;   // next-step token col
    int tok_n = tokrow[tsn];

    // ---- zx tile MFMA (uses prefetched ea; h-independent; overlaps the
    //      propagation of our drained primaries / in-flight mirrors) ----
    f32x4 acc[4];
#pragma unroll
    for (int cs = 0; cs < 4; ++cs) acc[cs] = {0.f, 0.f, 0.f, 0.f};
#pragma unroll
    for (int kt = 0; kt < 8; ++kt) {
#pragma unroll
      for (int cs = 0; cs < 4; ++cs) {
        short8 xb = *(const short8*)(&wx2[kt * 4 + q][cs * 64 + w * 16 + l16][0]);
        acc[cs] = __builtin_amdgcn_mfma_f32_16x16x32_bf16(ea[kt], xb, acc[cs], 0, 0, 0);
      }
    }

    // ---- poll (waves 0..2): producer p_w's full 16x64 tile.
    // Phase 1: sc0 primary, `limit` rounds with s_sleep backoff.
    // Phase 2 (guaranteed): sc1 mirror. First round's vmcnt(0) also drains
    // our in-flight mirror stores from the previous step.
    unsigned int tg = (unsigned int)t << 16;
    if (w < 3) {
      const unsigned int* qp = hb + buf * 4096 + pbase2;
      uint4v s0, s1, s2, s3;
      bool got = false;
      for (int it = 0; it < limit; ++it) {
        asm volatile(
            "global_load_dwordx4 %[s0], %[pp], off sc0\n\t"
            "global_load_dwordx4 %[s1], %[pp], off offset:16 sc0\n\t"
            "global_load_dwordx4 %[s2], %[pp], off offset:32 sc0\n\t"
            "global_load_dwordx4 %[s3], %[pp], off offset:48 sc0\n\t"
            "s_waitcnt vmcnt(0)"
            : [s0] "=&v"(s0), [s1] "=&v"(s1), [s2] "=&v"(s2), [s3] "=&v"(s3)
            : [pp] "v"(qp)
            : "memory");
        unsigned int bad = (s0[0] ^ tg) | (s0[1] ^ tg) | (s0[2] ^ tg) | (s0[3] ^ tg)
                         | (s1[0] ^ tg) | (s1[1] ^ tg) | (s1[2] ^ tg) | (s1[3] ^ tg)
                         | (s2[0] ^ tg) | (s2[1] ^ tg) | (s2[2] ^ tg) | (s2[3] ^ tg)
                         | (s3[0] ^ tg) | (s3[1] ^ tg) | (s3[2] ^ tg) | (s3[3] ^ tg);
        if (__all((bad & 0xffff0000u) == 0)) { got = true; break; }
        __builtin_amdgcn_s_sleep(2);           // backoff: relieve L2 line pressure
      }
      if (!got) {
        limit >>= 1;                           // sticky decay toward sc1-only
        const unsigned int* mp = qp + 65536;
        while (true) {
          asm volatile(
              "global_load_dwordx4 %[s0], %[pp], off sc1\n\t"
              "global_load_dwordx4 %[s1], %[pp], off offset:16 sc1\n\t"
              "global_load_dwordx4 %[s2], %[pp], off offset:32 sc1\n\t"
              "global_load_dwordx4 %[s3], %[pp], off offset:48 sc1\n\t"
              "s_waitcnt vmcnt(0)"
              : [s0] "=&v"(s0), [s1] "=&v"(s1), [s2] "=&v"(s2), [s3] "=&v"(s3)
              : [pp] "v"(mp)
              : "memory");
          unsigned int bad = (s0[0] ^ tg) | (s0[1] ^ tg) | (s0[2] ^ tg) | (s0[3] ^ tg)
                           | (s1[0] ^ tg) | (s1[1] ^ tg) | (s1[2] ^ tg) | (s1[3] ^ tg)
                           | (s2[0] ^ tg) | (s2[1] ^ tg) | (s2[2] ^ tg) | (s2[3] ^ tg)
                           | (s3[0] ^ tg) | (s3[1] ^ tg) | (s3[2] ^ tg) | (s3[3] ^ tg);
          if (__all((bad & 0xffff0000u) == 0)) break;
          __builtin_amdgcn_s_sleep(4);
        }
      }
      // deposit 16 bf16 into hl[buf] chunks (p_w*8 + pq4*2, +1), row prow2
      {
        uint4v d0, d1;
        d0[0] = __builtin_amdgcn_perm(s0[1], s0[0], 0x05040100u);
        d0[1] = __builtin_amdgcn_perm(s0[3], s0[2], 0x05040100u);
        d0[2] = __builtin_amdgcn_perm(s1[1], s1[0], 0x05040100u);
        d0[3] = __builtin_amdgcn_perm(s1[3], s1[2], 0x05040100u);
        d1[0] = __builtin_amdgcn_perm(s2[1], s2[0], 0x05040100u);
        d1[1] = __builtin_amdgcn_perm(s2[3], s2[2], 0x05040100u);
        d1[2] = __builtin_amdgcn_perm(s3[1], s3[0], 0x05040100u);
        d1[3] = __builtin_amdgcn_perm(s3[3], s3[2], 0x05040100u);
        int ch0 = p_w * 8 + pq4 * 2;
        *(uint4v*)(&hl[buf][ch0][prow2][0])     = d0;
        *(uint4v*)(&hl[buf][ch0 + 1][prow2][0]) = d1;
      }
    }

    // ---- emb prefetch for t+1 (flies during h-GEMM + epilogue) ----
    short8 ean[8];
    {
      const unsigned short* ern = embbf + (size_t)tok_n * 256 + q * 8;
#pragma unroll
      for (int kt = 0; kt < 8; ++kt) ean[kt] = *(const short8*)(ern + kt * 32);
    }

    __syncthreads();   // hl[buf] complete; also publishes prev epilogue writes

    // ---- h GEMM: A from LDS tile (conflict-free b128), B from regs ----
#pragma unroll
    for (int kt = 0; kt < 8; ++kt) {
      short8 ha = *(const short8*)(&hl[buf][kt * 4 + q][l16][0]);
#pragma unroll
      for (int cs = 0; cs < 4; ++cs)
        acc[cs] = __builtin_amdgcn_mfma_f32_16x16x32_bf16(ha, bfr[cs][kt], acc[cs], 0, 0, 0);
    }

    // ---- epilogue: gates, c/h update, LDS own-dims, dual tagged stores ----
    unsigned int* hwn = hb + ((buf ^ 1) * 4096) + srow;
    unsigned int wtag = ((unsigned int)(t + 1)) << 16;
    int dim = cg * 64 + w * 16 + l16;
    int chO = dim >> 3, eO = dim & 7;
    unsigned int sw[4];
#pragma unroll
    for (int r = 0; r < 4; ++r) {
      float iv = sigf(acc[0][r] + bv[0]);
      float fv = sigf(acc[1][r] + bv[1]);
      float gv = tanhf_(acc[2][r] + bv[2]);
      float ov = sigf(acc[3][r] + bv[3]);
      cst[r] = fv * cst[r] + iv * gv;
      float hv = ov * tanhf_(cst[r]);
      unsigned short h16 = f2bf(hv);
      sw[r] = wtag | (unsigned int)h16;
      hl[buf ^ 1][chO][q * 4 + r][eO] = h16;
    }
    // dual-publish: 4 sc0 primaries DRAINED (earliest L2 flush), then 4 sc1
    // mirrors undrained (ack drifts into next step's first poll wait).
    // The vmcnt(0) also retires the 8 emb loads (needed next step anyway).
    {
      unsigned int* hwm = hwn + 65536;
      asm volatile(
          "global_store_dword %[p], %[v0], off sc0\n\t"
          "global_store_dword %[p], %[v1], off offset:1024 sc0\n\t"
          "global_store_dword %[p], %[v2], off offset:2048 sc0\n\t"
          "global_store_dword %[p], %[v3], off offset:3072 sc0\n\t"
          "s_waitcnt vmcnt(0)\n\t"
          "global_store_dword %[m], %[v0], off sc1\n\t"
          "global_store_dword %[m], %[v1], off offset:1024 sc1\n\t"
          "global_store_dword %[m], %[v2], off offset:2048 sc1\n\t"
          "global_store_dword %[m], %[v3], off offset:3072 sc1"
          :: [p] "v"(hwn), [m] "v"(hwm), [v0] "v"(sw[0]), [v1] "v"(sw[1]),
             [v2] "v"(sw[2]), [v3] "v"(sw[3])
          : "memory");
    }

    // rotate emb prefetch
#pragma unroll
    for (int kt = 0; kt < 8; ++kt) ea[kt] = ean[kt];
  }
}

// ---------------------------------------------------------------------------
// K3: logits + softmax. 64 blocks (one per batch) x 64 threads (one wave).
// Final h_512 (tag 512, buf0) read from the PRIMARY buffers; the k2->k3
// dispatch boundary flushes caches (standard cross-kernel visibility).
__global__ __launch_bounds__(64) void k3_out(
    const unsigned int* __restrict__ hbufw,
    const float* __restrict__ wout, const float* __restrict__ bout,
    float* __restrict__ out) {
  int b = blockIdx.x, tid = threadIdx.x;
  int rg = b >> 4, r = b & 15;
  const unsigned int* hf  = hbufw + (size_t)rg * 8192 + r * 256;           // dir0 buf0
  const unsigned int* hbk = hbufw + 32768 + (size_t)rg * 8192 + r * 256;   // dir1 buf0
  float p[10];
#pragma unroll
  for (int l = 0; l < 10; l++) p[l] = 0.f;
  for (int k = tid; k < 512; k += 64) {
    unsigned int wd = (k < 256) ? hf[k] : hbk[k - 256];
    float f = bf2f((unsigned short)(wd & 0xffffu));
    const float* wr = wout + k * 10;
#pragma unroll
    for (int l = 0; l < 10; l++) p[l] += f * wr[l];
  }
#pragma unroll
  for (int off = 32; off; off >>= 1)
#pragma unroll
    for (int l = 0; l < 10; l++) p[l] += __shfl_down(p[l], off);
  if (tid == 0) {
    float lg[10], m = -1e30f;
#pragma unroll
    for (int l = 0; l < 10; l++) { lg[l] = p[l] + bout[l]; m = fmaxf(m, lg[l]); }
    float sum = 0.f;
#pragma unroll
    for (int l = 0; l < 10; l++) { lg[l] = __expf(lg[l] - m); sum += lg[l]; }
    float inv = 1.0f / sum;
#pragma unroll
    for (int l = 0; l < 10; l++) out[b * 10 + l] = lg[l] * inv;
  }
}

// ---------------------------------------------------------------------------
extern "C" void kernel_launch(void* const* d_in, const int* in_sizes, int n_in,
                              void* d_out, int out_size, void* d_ws, size_t ws_size,
                              hipStream_t stream) {
  const int*   tokens = (const int*)d_in[0];
  const float* emb    = (const float*)d_in[1];
  const float* wxf    = (const float*)d_in[2];
  const float* whf    = (const float*)d_in[3];
  const float* bf_    = (const float*)d_in[4];
  const float* wxb    = (const float*)d_in[5];
  const float* whb    = (const float*)d_in[6];
  const float* bb_    = (const float*)d_in[7];
  const float* wout   = (const float*)d_in[8];
  const float* bout   = (const float*)d_in[9];
  float* out = (float*)d_out;

  char* ws = (char*)d_ws;
  unsigned short* embbf = (unsigned short*)(ws + EMB16_OFF);
  unsigned short* wxt   = (unsigned short*)(ws + WXT_OFF);
  unsigned short* wht   = (unsigned short*)(ws + WHT_OFF);
  unsigned int*   hbufw = (unsigned int*)(ws + HBUF_OFF);
  (void)ws_size; (void)in_sizes; (void)n_in; (void)out_size;   // needs WS_NEED bytes

  // zero h0 (tag 0 == step 0) in primary, mirror, and desc area
  hipMemsetAsync(ws + HBUF_OFF, 0, 524416, stream);

  k0_transpose<<<dim3(8, 32, 4), 256, 0, stream>>>(wxf, wxb, whf, whb, wxt, wht);
  k0b_embcast<<<6250, 256, 0, stream>>>(emb, embbf);
  k2_rnn<<<32, 256, 0, stream>>>(tokens, embbf, wxt, wht, bf_, bb_, hbufw);
  k3_out<<<64, 64, 0, stream>>>(hbufw, wout, bout, out);
}

// Round 10
// 1372.370 us; speedup vs baseline: 1.1502x; 1.0040x over previous
//
#include <hip/hip_runtime.h>
#include <stdint.h>
#include <stddef.h>

// ---------------------------------------------------------------------------
// TextRNN: embed -> BiLSTM(512 steps) -> linear -> softmax   (MI355X gfx950)
//
// R12 (delta vs R11): BUFFER_INV before every poll round.
// Theory: consumer L1 staleness. CDNA L1 is write-through (producer's sc0
// store reaches XCD-L2 promptly), but sc0 LOADS may legally be served by
// the consumer's own L1 — and the spin re-reads the same addresses every
// round, keeping stale lines LRU-hot. Visibility then waits on incidental
// L1 eviction (~us-scale), insensitive to scope/drain/contention knobs —
// exactly the R5-R11 signature. Fix: `buffer_inv` (vector-L1 invalidate,
// CDNA3/4) at the top of each poll round -> every round reads true L2.
// Collateral ~0: all reused data is in LDS/registers.
// Everything else byte-identical to R11 (one-variable experiment):
//  - one polling wave per producer, s_sleep backoff
//  - producer drains 4 sc0 primaries before 4 sc1 mirrors (dual-publish,
//    hang-proof under any placement)
//  - runtime XCD-discovery grouping (same-XCD groups guaranteed)
// K0 : transpose/cast Wx,Wh -> bf16 [1024][256]
// K0b: cast emb table f32 -> bf16
// K2 : fused zx + recurrence (32 blocks = 8 groups x 4 cg, 256 thr)
// K3 : logits + softmax (reads primary; dispatch boundary flushes)
// ---------------------------------------------------------------------------

typedef __attribute__((ext_vector_type(8))) short   short8;
typedef __attribute__((ext_vector_type(4))) float   f32x4;
typedef __attribute__((ext_vector_type(4))) unsigned short ushort4v;
typedef __attribute__((ext_vector_type(4))) unsigned int   uint4v;
typedef __attribute__((ext_vector_type(2))) unsigned int   uint2v;

// ws byte offsets
#define EMB16_OFF ((size_t)0)            // 50000*256 bf16 = 25,600,000 B
#define WXT_OFF   ((size_t)25600000)     // 2*1024*256 bf16 = 1,048,576 B
#define WHT_OFF   ((size_t)26648576)     // 2*1024*256 bf16 = 1,048,576 B
#define HBUF_OFF  ((size_t)27697152)     // primary 262144 + mirror 262144 + desc 128
#define WS_NEED   ((size_t)28221568)

__device__ __forceinline__ unsigned short f2bf(float f) {
  unsigned int u = __builtin_bit_cast(unsigned int, f);
  u += 0x7fffu + ((u >> 16) & 1u);            // RNE
  return (unsigned short)(u >> 16);
}
__device__ __forceinline__ float bf2f(unsigned short b) {
  unsigned int u = ((unsigned int)b) << 16;
  return __builtin_bit_cast(float, u);
}
__device__ __forceinline__ float sigf(float x) { return 1.0f / (1.0f + __expf(-x)); }
__device__ __forceinline__ float tanhf_(float x) {
  float t = __expf(-2.0f * fabsf(x));
  float r = (1.0f - t) / (1.0f + t);          // no inf/NaN for any x
  return copysignf(r, x);
}

// ---------------------------------------------------------------------------
// K0: W (f32 [256][1024]) -> Wt (bf16 [1024][256]).  z selects matrix.
__global__ __launch_bounds__(256) void k0_transpose(
    const float* __restrict__ wxf, const float* __restrict__ wxb,
    const float* __restrict__ whf, const float* __restrict__ whb,
    unsigned short* __restrict__ wxt, unsigned short* __restrict__ wht) {
  __shared__ float lds[32][33];
  int mat = blockIdx.z;
  const float* src = (mat == 0) ? wxf : (mat == 1) ? wxb : (mat == 2) ? whf : whb;
  unsigned short* dst = (mat == 0) ? wxt : (mat == 1) ? (wxt + 262144)
                      : (mat == 2) ? wht : (wht + 262144);
  int k0 = blockIdx.x * 32;
  int n0 = blockIdx.y * 32;
  int tx = threadIdx.x & 31, ty = threadIdx.x >> 5;   // ty 0..7
#pragma unroll
  for (int r = 0; r < 4; r++) {
    int k = ty + r * 8;
    lds[k][tx] = src[(size_t)(k0 + k) * 1024 + n0 + tx];
  }
  __syncthreads();
#pragma unroll
  for (int r = 0; r < 4; r++) {
    int n = ty + r * 8;
    dst[(size_t)(n0 + n) * 256 + k0 + tx] = f2bf(lds[tx][n]);
  }
}

// ---------------------------------------------------------------------------
// K0b: emb table f32 -> bf16.  50000*256 = 12.8M elems, 8/thread, 6250 blocks.
__global__ __launch_bounds__(256) void k0b_embcast(
    const float* __restrict__ emb, unsigned short* __restrict__ embbf) {
  size_t i = ((size_t)blockIdx.x * 256 + threadIdx.x) * 8;
  f32x4 v0 = *(const f32x4*)(emb + i);
  f32x4 v1 = *(const f32x4*)(emb + i + 4);
  short8 st;
#pragma unroll
  for (int j = 0; j < 4; j++) {
    st[j]     = (short)f2bf(v0[j]);
    st[4 + j] = (short)f2bf(v1[j]);
  }
  *(short8*)(embbf + i) = st;
}

// ---------------------------------------------------------------------------
// K2: fused zx + recurrence. 32 blocks, 256 thr (4 waves).
// DYNAMIC grouping (R10): rank of key (xcc<<8|bid) in sorted order of all
// 32 keys; group g = rank>>2 -> (d = g>>2, rg = g&3); member cg = rank&3.
// Block (d,rg,cg): batch rows rg*16..+16, h-dims cg*64..+64 (all 4 gates).
// Wave w: dims w*16..+16; lane (q,l16): rows q*4..+4, dim w*16+l16;
// gate-major accumulators (cs = gate) -> c-state in registers.
// hbuf primary: [g][buf][row 16][dim 256] tagged u32 ((t<<16)|bf16), sc0.
// hbuf mirror : same layout at +65536 words, sc1. desc: +131072 words.
// POLL: wave w<3 polls producer p=(cg+1+w)&3's full tile; lane l:
// row = l>>2, 16-dim quad q4 = l&3; buffer_inv before each round.
__global__ __launch_bounds__(256, 1) void k2_rnn(
    const int* __restrict__ tokens, const unsigned short* __restrict__ embbf,
    const unsigned short* __restrict__ wxt,   // [2][1024][256] bf16
    const unsigned short* __restrict__ wht,   // [2][1024][256] bf16
    const float* __restrict__ bf_, const float* __restrict__ bb_,
    unsigned int* __restrict__ hbufw) {
  int bx = blockIdx.x;
  int tid = threadIdx.x;
  int w = tid >> 6, lane = tid & 63, q = lane >> 4, l16 = lane & 15;

  // ---- XCD discovery & dynamic group assignment ----
  unsigned int* desc = hbufw + 131072;
  {
    unsigned int xcc = __builtin_amdgcn_s_getreg((31 << 11) | 20) & 0xffu;  // HW_REG_XCC_ID
    if (tid == 0) {
      unsigned int v = 0x100u | xcc;
      asm volatile("global_store_dword %0, %1, off sc1"
                   :: "v"(desc + bx), "v"(v) : "memory");
    }
  }
  int g, cg;
  {
    const unsigned int* dp = desc + (lane & 31);
    unsigned int dv;
    while (true) {
      asm volatile("buffer_inv\n\tglobal_load_dword %0, %1, off sc1\n\ts_waitcnt vmcnt(0)"
                   : "=&v"(dv) : "v"(dp) : "memory");
      if (__all((dv & 0x100u) != 0u)) break;
    }
    unsigned int key = ((dv & 0xffu) << 8) | (unsigned int)(lane & 31);
    int rank = 0;
#pragma unroll
    for (int j = 0; j < 32; ++j) {
      unsigned int kj = __shfl(key, j);
      rank += (kj < key) ? 1 : 0;
    }
    int myrank = __shfl(rank, bx);   // our block's rank (bx < 32)
    g  = myrank >> 2;
    cg = myrank & 3;
  }
  int d  = g >> 2;
  int rg = g & 3;

  __shared__ unsigned short wx2[32][256][8];    // Wx slice, interleaved: 131072 B
  __shared__ unsigned short hl[2][32][16][8];   // h tiles, interleaved:   16384 B

  // ---- preload Wx slice (block cols: gate*256 + cg*64 + dl) into wx2 ----
  const unsigned short* wxd = wxt + (size_t)d * 262144;
  for (int it = 0; it < 32; ++it) {
    int idx = it * 256 + tid;                 // 8192 16B-chunks
    int cl = idx & 255, ch = idx >> 8;        // cl = cs*64+dl, ch = kt*4+q
    int gcol = (cl >> 6) * 256 + cg * 64 + (cl & 63);
    *(short8*)(&wx2[ch][cl][0]) = *(const short8*)(wxd + (size_t)gcol * 256 + ch * 8);
  }

  // ---- Wh B-fragments resident in registers (128 regs/lane) ----
  const unsigned short* whd = wht + (size_t)d * 262144;
  short8 bfr[4][8];
#pragma unroll
  for (int cs = 0; cs < 4; cs++) {
    const unsigned short* wp = whd + (size_t)(cs * 256 + cg * 64 + w * 16 + l16) * 256;
#pragma unroll
    for (int kt = 0; kt < 8; kt++)
      bfr[cs][kt] = *(const short8*)(wp + kt * 32 + q * 8);
  }

  // zero h LDS tiles (h0 = 0)
  {
    unsigned int* hlw = (unsigned int*)&hl[0][0][0][0];
    for (int i = tid; i < 4096; i += 256) hlw[i] = 0;
  }
  __syncthreads();

  const float* bias = d ? bb_ : bf_;
  float bv[4];
#pragma unroll
  for (int cs = 0; cs < 4; cs++) bv[cs] = bias[cs * 256 + cg * 64 + w * 16 + l16];

  float cst[4] = {0.f, 0.f, 0.f, 0.f};        // c for (row=q*4+r, dim=w*16+l16)
  unsigned int* hb = hbufw + (size_t)g * 8192;              // primary
  int srow  = (q * 4) * 256 + cg * 64 + w * 16 + l16;       // producer base
  const int* tokrow = tokens + (rg * 16 + l16) * 512;

  // poll geometry (waves 0..2 only)
  int p_w   = (cg + 1 + w) & 3;               // this wave's producer
  int prow2 = lane >> 2;                      // row 0..15
  int pq4   = lane & 3;                       // 16-dim quad within 64
  int pbase2 = prow2 * 256 + p_w * 64 + pq4 * 16;   // word offset

  int limit = 16;                              // adaptive sc0 poll budget

  // prologue: emb row for t=0
  short8 ea[8];
  {
    int ts0 = d ? 511 : 0;
    int tok0 = tokrow[ts0];
    const unsigned short* er = embbf + (size_t)tok0 * 256 + q * 8;
#pragma unroll
    for (int kt = 0; kt < 8; ++kt) ea[kt] = *(const short8*)(er + kt * 32);
  }

  for (int t = 0; t < 512; ++t) {
    int buf = t & 1;
    int tsn = (t < 511) ? (d ? 510 - t : t + 1) : 0;   // next-step token col
    int tok_n = tokrow[tsn];

    // ---- zx tile MFMA (uses prefetched ea; h-independent; overlaps the
    //      propagation of our drained primaries / in-flight mirrors) ----
    f32x4 acc[4];
#pragma unroll
    for (int cs = 0; cs < 4; ++cs) acc[cs] = {0.f, 0.f, 0.f, 0.f};
#pragma unroll
    for (int kt = 0; kt < 8; ++kt) {
#pragma unroll
      for (int cs = 0; cs < 4; ++cs) {
        short8 xb = *(const short8*)(&wx2[kt * 4 + q][cs * 64 + w * 16 + l16][0]);
        acc[cs] = __builtin_amdgcn_mfma_f32_16x16x32_bf16(ea[kt], xb, acc[cs], 0, 0, 0);
      }
    }

    // ---- poll (waves 0..2): producer p_w's full 16x64 tile.
    // buffer_inv before EACH round: drop stale L1 lines so sc0 loads read
    // true XCD-L2 content (the decisive change this round).
    unsigned int tg = (unsigned int)t << 16;
    if (w < 3) {
      const unsigned int* qp = hb + buf * 4096 + pbase2;
      uint4v s0, s1, s2, s3;
      bool got = false;
      for (int it = 0; it < limit; ++it) {
        asm volatile(
            "buffer_inv\n\t"
            "global_load_dwordx4 %[s0], %[pp], off sc0\n\t"
            "global_load_dwordx4 %[s1], %[pp], off offset:16 sc0\n\t"
            "global_load_dwordx4 %[s2], %[pp], off offset:32 sc0\n\t"
            "global_load_dwordx4 %[s3], %[pp], off offset:48 sc0\n\t"
            "s_waitcnt vmcnt(0)"
            : [s0] "=&v"(s0), [s1] "=&v"(s1), [s2] "=&v"(s2), [s3] "=&v"(s3)
            : [pp] "v"(qp)
            : "memory");
        unsigned int bad = (s0[0] ^ tg) | (s0[1] ^ tg) | (s0[2] ^ tg) | (s0[3] ^ tg)
                         | (s1[0] ^ tg) | (s1[1] ^ tg) | (s1[2] ^ tg) | (s1[3] ^ tg)
                         | (s2[0] ^ tg) | (s2[1] ^ tg) | (s2[2] ^ tg) | (s2[3] ^ tg)
                         | (s3[0] ^ tg) | (s3[1] ^ tg) | (s3[2] ^ tg) | (s3[3] ^ tg);
        if (__all((bad & 0xffff0000u) == 0)) { got = true; break; }
        __builtin_amdgcn_s_sleep(2);           // backoff: relieve L2 line pressure
      }
      if (!got) {
        limit >>= 1;                           // sticky decay toward sc1-only
        const unsigned int* mp = qp + 65536;
        while (true) {
          asm volatile(
              "buffer_inv\n\t"
              "global_load_dwordx4 %[s0], %[pp], off sc1\n\t"
              "global_load_dwordx4 %[s1], %[pp], off offset:16 sc1\n\t"
              "global_load_dwordx4 %[s2], %[pp], off offset:32 sc1\n\t"
              "global_load_dwordx4 %[s3], %[pp], off offset:48 sc1\n\t"
              "s_waitcnt vmcnt(0)"
              : [s0] "=&v"(s0), [s1] "=&v"(s1), [s2] "=&v"(s2), [s3] "=&v"(s3)
              : [pp] "v"(mp)
              : "memory");
          unsigned int bad = (s0[0] ^ tg) | (s0[1] ^ tg) | (s0[2] ^ tg) | (s0[3] ^ tg)
                           | (s1[0] ^ tg) | (s1[1] ^ tg) | (s1[2] ^ tg) | (s1[3] ^ tg)
                           | (s2[0] ^ tg) | (s2[1] ^ tg) | (s2[2] ^ tg) | (s2[3] ^ tg)
                           | (s3[0] ^ tg) | (s3[1] ^ tg) | (s3[2] ^ tg) | (s3[3] ^ tg);
          if (__all((bad & 0xffff0000u) == 0)) break;
          __builtin_amdgcn_s_sleep(4);
        }
      }
      // deposit 16 bf16 into hl[buf] chunks (p_w*8 + pq4*2, +1), row prow2
      {
        uint4v d0, d1;
        d0[0] = __builtin_amdgcn_perm(s0[1], s0[0], 0x05040100u);
        d0[1] = __builtin_amdgcn_perm(s0[3], s0[2], 0x05040100u);
        d0[2] = __builtin_amdgcn_perm(s1[1], s1[0], 0x05040100u);
        d0[3] = __builtin_amdgcn_perm(s1[3], s1[2], 0x05040100u);
        d1[0] = __builtin_amdgcn_perm(s2[1], s2[0], 0x05040100u);
        d1[1] = __builtin_amdgcn_perm(s2[3], s2[2], 0x05040100u);
        d1[2] = __builtin_amdgcn_perm(s3[1], s3[0], 0x05040100u);
        d1[3] = __builtin_amdgcn_perm(s3[3], s3[2], 0x05040100u);
        int ch0 = p_w * 8 + pq4 * 2;
        *(uint4v*)(&hl[buf][ch0][prow2][0])     = d0;
        *(uint4v*)(&hl[buf][ch0 + 1][prow2][0]) = d1;
      }
    }

    // ---- emb prefetch for t+1 (flies during h-GEMM + epilogue) ----
    short8 ean[8];
    {
      const unsigned short* ern = embbf + (size_t)tok_n * 256 + q * 8;
#pragma unroll
      for (int kt = 0; kt < 8; ++kt) ean[kt] = *(const short8*)(ern + kt * 32);
    }

    __syncthreads();   // hl[buf] complete; also publishes prev epilogue writes

    // ---- h GEMM: A from LDS tile (conflict-free b128), B from regs ----
#pragma unroll
    for (int kt = 0; kt < 8; ++kt) {
      short8 ha = *(const short8*)(&hl[buf][kt * 4 + q][l16][0]);
#pragma unroll
      for (int cs = 0; cs < 4; ++cs)
        acc[cs] = __builtin_amdgcn_mfma_f32_16x16x32_bf16(ha, bfr[cs][kt], acc[cs], 0, 0, 0);
    }

    // ---- epilogue: gates, c/h update, LDS own-dims, dual tagged stores ----
    unsigned int* hwn = hb + ((buf ^ 1) * 4096) + srow;
    unsigned int wtag = ((unsigned int)(t + 1)) << 16;
    int dim = cg * 64 + w * 16 + l16;
    int chO = dim >> 3, eO = dim & 7;
    unsigned int sw[4];
#pragma unroll
    for (int r = 0; r < 4; ++r) {
      float iv = sigf(acc[0][r] + bv[0]);
      float fv = sigf(acc[1][r] + bv[1]);
      float gv = tanhf_(acc[2][r] + bv[2]);
      float ov = sigf(acc[3][r] + bv[3]);
      cst[r] = fv * cst[r] + iv * gv;
      float hv = ov * tanhf_(cst[r]);
      unsigned short h16 = f2bf(hv);
      sw[r] = wtag | (unsigned int)h16;
      hl[buf ^ 1][chO][q * 4 + r][eO] = h16;
    }
    // dual-publish: 4 sc0 primaries DRAINED (earliest L2 flush), then 4 sc1
    // mirrors undrained (ack drifts into next step's first poll wait).
    // The vmcnt(0) also retires the 8 emb loads (needed next step anyway).
    {
      unsigned int* hwm = hwn + 65536;
      asm volatile(
          "global_store_dword %[p], %[v0], off sc0\n\t"
          "global_store_dword %[p], %[v1], off offset:1024 sc0\n\t"
          "global_store_dword %[p], %[v2], off offset:2048 sc0\n\t"
          "global_store_dword %[p], %[v3], off offset:3072 sc0\n\t"
          "s_waitcnt vmcnt(0)\n\t"
          "global_store_dword %[m], %[v0], off sc1\n\t"
          "global_store_dword %[m], %[v1], off offset:1024 sc1\n\t"
          "global_store_dword %[m], %[v2], off offset:2048 sc1\n\t"
          "global_store_dword %[m], %[v3], off offset:3072 sc1"
          :: [p] "v"(hwn), [m] "v"(hwm), [v0] "v"(sw[0]), [v1] "v"(sw[1]),
             [v2] "v"(sw[2]), [v3] "v"(sw[3])
          : "memory");
    }

    // rotate emb prefetch
#pragma unroll
    for (int kt = 0; kt < 8; ++kt) ea[kt] = ean[kt];
  }
}

// ---------------------------------------------------------------------------
// K3: logits + softmax. 64 blocks (one per batch) x 64 threads (one wave).
// Final h_512 (tag 512, buf0) read from the PRIMARY buffers; the k2->k3
// dispatch boundary flushes caches (standard cross-kernel visibility).
__global__ __launch_bounds__(64) void k3_out(
    const unsigned int* __restrict__ hbufw,
    const float* __restrict__ wout, const float* __restrict__ bout,
    float* __restrict__ out) {
  int b = blockIdx.x, tid = threadIdx.x;
  int rg = b >> 4, r = b & 15;
  const unsigned int* hf  = hbufw + (size_t)rg * 8192 + r * 256;           // dir0 buf0
  const unsigned int* hbk = hbufw + 32768 + (size_t)rg * 8192 + r * 256;   // dir1 buf0
  float p[10];
#pragma unroll
  for (int l = 0; l < 10; l++) p[l] = 0.f;
  for (int k = tid; k < 512; k += 64) {
    unsigned int wd = (k < 256) ? hf[k] : hbk[k - 256];
    float f = bf2f((unsigned short)(wd & 0xffffu));
    const float* wr = wout + k * 10;
#pragma unroll
    for (int l = 0; l < 10; l++) p[l] += f * wr[l];
  }
#pragma unroll
  for (int off = 32; off; off >>= 1)
#pragma unroll
    for (int l = 0; l < 10; l++) p[l] += __shfl_down(p[l], off);
  if (tid == 0) {
    float lg[10], m = -1e30f;
#pragma unroll
    for (int l = 0; l < 10; l++) { lg[l] = p[l] + bout[l]; m = fmaxf(m, lg[l]); }
    float sum = 0.f;
#pragma unroll
    for (int l = 0; l < 10; l++) { lg[l] = __expf(lg[l] - m); sum += lg[l]; }
    float inv = 1.0f / sum;
#pragma unroll
    for (int l = 0; l < 10; l++) out[b * 10 + l] = lg[l] * inv;
  }
}

// ---------------------------------------------------------------------------
extern "C" void kernel_launch(void* const* d_in, const int* in_sizes, int n_in,
                              void* d_out, int out_size, void* d_ws, size_t ws_size,
                              hipStream_t stream) {
  const int*   tokens = (const int*)d_in[0];
  const float* emb    = (const float*)d_in[1];
  const float* wxf    = (const float*)d_in[2];
  const float* whf    = (const float*)d_in[3];
  const float* bf_    = (const float*)d_in[4];
  const float* wxb    = (const float*)d_in[5];
  const float* whb    = (const float*)d_in[6];
  const float* bb_    = (const float*)d_in[7];
  const float* wout   = (const float*)d_in[8];
  const float* bout   = (const float*)d_in[9];
  float* out = (float*)d_out;

  char* ws = (char*)d_ws;
  unsigned short* embbf = (unsigned short*)(ws + EMB16_OFF);
  unsigned short* wxt   = (unsigned short*)(ws + WXT_OFF);
  unsigned short* wht   = (unsigned short*)(ws + WHT_OFF);
  unsigned int*   hbufw = (unsigned int*)(ws + HBUF_OFF);
  (void)ws_size; (void)in_sizes; (void)n_in; (void)out_size;   // needs WS_NEED bytes

  // zero h0 (tag 0 == step 0) in primary, mirror, and desc area
  hipMemsetAsync(ws + HBUF_OFF, 0, 524416, stream);

  k0_transpose<<<dim3(8, 32, 4), 256, 0, stream>>>(wxf, wxb, whf, whb, wxt, wht);
  k0b_embcast<<<6250, 256, 0, stream>>>(emb, embbf);
  k2_rnn<<<32, 256, 0, stream>>>(tokens, embbf, wxt, wht, bf_, bb_, hbufw);
  k3_out<<<64, 64, 0, stream>>>(hbufw, wout, bout, out);
}